// Round 1
// baseline (5285.226 us; speedup 1.0000x reference)
//
#include <hip/hip_runtime.h>
#include <math.h>

#define D_MODEL 1024
#define N_HEADS 16
#define HEAD_DIM 64
#define MAX_REL 16
#define SEQ 1024
#define BATCH 4

// ---------------- GEMM: C = A * W^T + bias ----------------
// A: [M,K] row-major, W: [N,K] row-major, C: [M,N]
// BM=BN=64, BK=16, 256 threads, 4x4 acc per thread.
#define BM 64
#define BN 64
#define BK 16

__global__ __launch_bounds__(256) void gemm_bt_bias(
    const float* __restrict__ A,
    const float* __restrict__ W,
    const float* __restrict__ bias,
    float* __restrict__ C, int M, int N, int K)
{
    __shared__ float As[BK][BM];
    __shared__ float Bs[BK][BN];
    const int tid = threadIdx.x;
    const int tx = tid % 16, ty = tid / 16;
    const int m0 = blockIdx.y * BM, n0 = blockIdx.x * BN;

    float acc[4][4] = {};
    const int lr = tid / 4;        // 0..63  row within tile
    const int lc = (tid % 4) * 4;  // 0,4,8,12  col within k-tile

    for (int k0 = 0; k0 < K; k0 += BK) {
        float4 a4 = *(const float4*)(A + (size_t)(m0 + lr) * K + k0 + lc);
        float4 b4 = *(const float4*)(W + (size_t)(n0 + lr) * K + k0 + lc);
        As[lc+0][lr] = a4.x; As[lc+1][lr] = a4.y; As[lc+2][lr] = a4.z; As[lc+3][lr] = a4.w;
        Bs[lc+0][lr] = b4.x; Bs[lc+1][lr] = b4.y; Bs[lc+2][lr] = b4.z; Bs[lc+3][lr] = b4.w;
        __syncthreads();
        #pragma unroll
        for (int kk = 0; kk < BK; ++kk) {
            float av[4], bv[4];
            #pragma unroll
            for (int i = 0; i < 4; ++i) av[i] = As[kk][ty*4+i];
            #pragma unroll
            for (int j = 0; j < 4; ++j) bv[j] = Bs[kk][tx*4+j];
            #pragma unroll
            for (int i = 0; i < 4; ++i)
                #pragma unroll
                for (int j = 0; j < 4; ++j)
                    acc[i][j] += av[i] * bv[j];
        }
        __syncthreads();
    }
    #pragma unroll
    for (int i = 0; i < 4; ++i) {
        const int m = m0 + ty*4 + i;
        const int n = n0 + tx*4;
        float4 o;
        o.x = acc[i][0] + bias[n+0];
        o.y = acc[i][1] + bias[n+1];
        o.z = acc[i][2] + bias[n+2];
        o.w = acc[i][3] + bias[n+3];
        *(float4*)(C + (size_t)m * N + n) = o;
    }
}

// ---------------- Attention ----------------
// One block (256 threads) per (b, h, qi). Softmax over 1024 keys in LDS.
// attn2 term via 33 precomputed dots (pbias); emb_v folded into PV loop.
__global__ __launch_bounds__(256) void attn_kernel(
    const float* __restrict__ q, const float* __restrict__ k,
    const float* __restrict__ v, const int* __restrict__ mask,
    const float* __restrict__ emb_k, const float* __restrict__ emb_v,
    float* __restrict__ x)
{
    const int qi = blockIdx.x;
    const int h  = blockIdx.y;
    const int b  = blockIdx.z;
    const int tid = threadIdx.x;

    __shared__ float qv[HEAD_DIM];
    __shared__ float ek[33*HEAD_DIM];
    __shared__ float ev[33*HEAD_DIM];
    __shared__ float pbias[33];
    __shared__ float logit[SEQ];
    __shared__ float red[256];
    __shared__ float partial[4][HEAD_DIM];

    const size_t qoff = ((size_t)(b*SEQ + qi)) * D_MODEL + h*HEAD_DIM;
    if (tid < HEAD_DIM) qv[tid] = q[qoff + tid];
    for (int i = tid; i < 33*HEAD_DIM; i += 256) {
        ek[i] = emb_k[i];
        ev[i] = emb_v[i];
    }
    __syncthreads();

    if (tid < 33) {
        float s = 0.f;
        #pragma unroll
        for (int d = 0; d < HEAD_DIM; ++d) s += qv[d] * ek[tid*HEAD_DIM + d];
        pbias[tid] = s;
    }
    __syncthreads();

    const float inv_scale = 0.125f;  // 1/sqrt(64)
    const int* mrow = mask + ((size_t)b*SEQ + qi)*SEQ;
    for (int ki = tid; ki < SEQ; ki += 256) {
        int dist = ki - qi;
        dist = dist < -MAX_REL ? -MAX_REL : (dist > MAX_REL ? MAX_REL : dist);
        const int idx = dist + MAX_REL;
        const float* kp = k + ((size_t)(b*SEQ + ki))*D_MODEL + h*HEAD_DIM;
        float s = 0.f;
        #pragma unroll
        for (int d4 = 0; d4 < HEAD_DIM; d4 += 4) {
            float4 k4 = *(const float4*)(kp + d4);
            s += qv[d4+0]*k4.x + qv[d4+1]*k4.y + qv[d4+2]*k4.z + qv[d4+3]*k4.w;
        }
        float l = (s + pbias[idx]) * inv_scale;
        if (mrow[ki] == 0) l = -1e30f;
        logit[ki] = l;
    }
    __syncthreads();

    // block max
    float lm = -1e30f;
    for (int ki = tid; ki < SEQ; ki += 256) lm = fmaxf(lm, logit[ki]);
    red[tid] = lm; __syncthreads();
    for (int s = 128; s > 0; s >>= 1) {
        if (tid < s) red[tid] = fmaxf(red[tid], red[tid+s]);
        __syncthreads();
    }
    const float m = red[0];
    __syncthreads();

    // exp + block sum
    float ls = 0.f;
    for (int ki = tid; ki < SEQ; ki += 256) {
        float e = __expf(logit[ki] - m);
        logit[ki] = e;
        ls += e;
    }
    red[tid] = ls; __syncthreads();
    for (int s = 128; s > 0; s >>= 1) {
        if (tid < s) red[tid] += red[tid+s];
        __syncthreads();
    }
    const float inv_denom = 1.f / red[0];
    __syncthreads();

    // PV: acc[d] = sum_k p[k] * (v[b,k,h,d] + emb_v[idx(q,k),d])
    const int d = tid & 63;
    const int g = tid >> 6;
    float acc = 0.f;
    for (int ki = g; ki < SEQ; ki += 4) {
        const float p = logit[ki];
        int dist = ki - qi;
        dist = dist < -MAX_REL ? -MAX_REL : (dist > MAX_REL ? MAX_REL : dist);
        const int idx = dist + MAX_REL;
        acc += p * (v[((size_t)(b*SEQ + ki))*D_MODEL + h*HEAD_DIM + d] + ev[idx*HEAD_DIM + d]);
    }
    partial[g][d] = acc;
    __syncthreads();
    if (tid < HEAD_DIM) {
        const float o = (partial[0][tid] + partial[1][tid] + partial[2][tid] + partial[3][tid]) * inv_denom;
        x[qoff + tid] = o;
    }
}

extern "C" void kernel_launch(void* const* d_in, const int* in_sizes, int n_in,
                              void* d_out, int out_size, void* d_ws, size_t ws_size,
                              hipStream_t stream) {
    const float* query = (const float*)d_in[0];
    const float* key   = (const float*)d_in[1];
    const float* value = (const float*)d_in[2];
    const int*   mask  = (const int*)d_in[3];
    const float* Wq = (const float*)d_in[4];
    const float* bq = (const float*)d_in[5];
    const float* Wk = (const float*)d_in[6];
    const float* bk = (const float*)d_in[7];
    const float* Wv = (const float*)d_in[8];
    const float* bv = (const float*)d_in[9];
    const float* Wo = (const float*)d_in[10];
    const float* bo = (const float*)d_in[11];
    const float* emb_k = (const float*)d_in[12];
    const float* emb_v = (const float*)d_in[13];
    float* out = (float*)d_out;
    float* ws  = (float*)d_ws;

    const int M = BATCH * SEQ;  // 4096
    float* qb = ws;
    float* kb = qb + (size_t)M * D_MODEL;
    float* vb = kb + (size_t)M * D_MODEL;
    float* xb = vb + (size_t)M * D_MODEL;

    dim3 gB(D_MODEL / BN, M / BM), tB(256);
    gemm_bt_bias<<<gB, tB, 0, stream>>>(query, Wq, bq, qb, M, D_MODEL, D_MODEL);
    gemm_bt_bias<<<gB, tB, 0, stream>>>(key,   Wk, bk, kb, M, D_MODEL, D_MODEL);
    gemm_bt_bias<<<gB, tB, 0, stream>>>(value, Wv, bv, vb, M, D_MODEL, D_MODEL);

    dim3 gA(SEQ, N_HEADS, BATCH);
    attn_kernel<<<gA, dim3(256), 0, stream>>>(qb, kb, vb, mask, emb_k, emb_v, xb);

    gemm_bt_bias<<<gB, tB, 0, stream>>>(xb, Wo, bo, out, M, D_MODEL, D_MODEL);
}

// Round 2
// 954.372 us; speedup vs baseline: 5.5379x; 5.5379x over previous
//
#include <hip/hip_runtime.h>
#include <math.h>

#define D_MODEL 1024
#define N_HEADS 16
#define HEAD_DIM 64
#define MAX_REL 16
#define SEQ 1024
#define BATCH 4

// ---------------- GEMM: C = A * W^T + bias ----------------
#define BM 64
#define BN 64
#define BK 16

__global__ __launch_bounds__(256) void gemm_bt_bias(
    const float* __restrict__ A,
    const float* __restrict__ W,
    const float* __restrict__ bias,
    float* __restrict__ C, int M, int N, int K)
{
    __shared__ float As[BK][BM];
    __shared__ float Bs[BK][BN];
    const int tid = threadIdx.x;
    const int tx = tid % 16, ty = tid / 16;
    const int m0 = blockIdx.y * BM, n0 = blockIdx.x * BN;

    float acc[4][4] = {};
    const int lr = tid / 4;
    const int lc = (tid % 4) * 4;

    for (int k0 = 0; k0 < K; k0 += BK) {
        float4 a4 = *(const float4*)(A + (size_t)(m0 + lr) * K + k0 + lc);
        float4 b4 = *(const float4*)(W + (size_t)(n0 + lr) * K + k0 + lc);
        As[lc+0][lr] = a4.x; As[lc+1][lr] = a4.y; As[lc+2][lr] = a4.z; As[lc+3][lr] = a4.w;
        Bs[lc+0][lr] = b4.x; Bs[lc+1][lr] = b4.y; Bs[lc+2][lr] = b4.z; Bs[lc+3][lr] = b4.w;
        __syncthreads();
        #pragma unroll
        for (int kk = 0; kk < BK; ++kk) {
            float av[4], bv[4];
            #pragma unroll
            for (int i = 0; i < 4; ++i) av[i] = As[kk][ty*4+i];
            #pragma unroll
            for (int j = 0; j < 4; ++j) bv[j] = Bs[kk][tx*4+j];
            #pragma unroll
            for (int i = 0; i < 4; ++i)
                #pragma unroll
                for (int j = 0; j < 4; ++j)
                    acc[i][j] += av[i] * bv[j];
        }
        __syncthreads();
    }
    #pragma unroll
    for (int i = 0; i < 4; ++i) {
        const int m = m0 + ty*4 + i;
        const int n = n0 + tx*4;
        float4 o;
        o.x = acc[i][0] + bias[n+0];
        o.y = acc[i][1] + bias[n+1];
        o.z = acc[i][2] + bias[n+2];
        o.w = acc[i][3] + bias[n+3];
        *(float4*)(C + (size_t)m * N + n) = o;
    }
}

// ---------------- Flash attention with relative position ----------------
// Block = 64 queries x one (b,h). K-tiles of 64 staged in LDS, online softmax.
// attn2 via pb[q][33] = q . emb_k^T; weight2 via exact band probs + tail sums.
#define QT 64
#define KT 64
#define PAD 68   // padded LDS row stride (floats), keeps float4 alignment

__global__ __launch_bounds__(256) void attn_flash(
    const float* __restrict__ q, const float* __restrict__ k,
    const float* __restrict__ v, const int* __restrict__ mask,
    const float* __restrict__ emb_k, const float* __restrict__ emb_v,
    float* __restrict__ x)
{
    __shared__ float Qs[HEAD_DIM * PAD];   // transposed: [d][q]
    __shared__ float KP[KT * PAD];         // K phase: [d][k]; P phase: [k][q]
    __shared__ float Vs[KT * PAD];         // natural: [k][d]
    __shared__ float pb[QT * 33];          // per-q position bias dots
    __shared__ float band[QT * 33];        // exact band probabilities
    __shared__ float red_s[QT * 17];
    __shared__ float red_t[QT * 17];
    __shared__ float m_sh[QT], l_sh[QT], rt_sh[QT], al_sh[QT];

    const int qt = blockIdx.x, h = blockIdx.y, b = blockIdx.z;
    const int q0 = qt * QT;
    const int tid = threadIdx.x;
    const int tx = tid & 15, ty = tid >> 4;
    const int lr = tid >> 2;            // staging row 0..63
    const int lc = (tid & 3) * 16;      // staging col base

    // ---- load Q tile transposed ----
    {
        const float* qp = q + ((size_t)(b*SEQ + q0 + lr))*D_MODEL + h*HEAD_DIM + lc;
        float4 t0 = *(const float4*)(qp + 0);
        float4 t1 = *(const float4*)(qp + 4);
        float4 t2 = *(const float4*)(qp + 8);
        float4 t3 = *(const float4*)(qp + 12);
        float tmp[16] = {t0.x,t0.y,t0.z,t0.w, t1.x,t1.y,t1.z,t1.w,
                         t2.x,t2.y,t2.z,t2.w, t3.x,t3.y,t3.z,t3.w};
        #pragma unroll
        for (int i = 0; i < 16; ++i) Qs[(lc+i)*PAD + lr] = tmp[i];
    }
    for (int i = tid; i < QT*33; i += 256) band[i] = 0.f;
    if (tid < QT) { m_sh[tid] = -1e30f; l_sh[tid] = 0.f; rt_sh[tid] = 0.f; }
    __syncthreads();

    // ---- pb[q][j] = sum_d Q[q][d] * emb_k[j][d] ----
    for (int idx = tid; idx < QT*33; idx += 256) {
        const int qq = idx & 63, j = idx >> 6;
        float s = 0.f;
        #pragma unroll 8
        for (int d = 0; d < HEAD_DIM; ++d) s += Qs[d*PAD + qq] * emb_k[j*HEAD_DIM + d];
        pb[qq*33 + j] = s;
    }

    float O[4][4] = {};
    const float inv_scale = 0.125f;

    for (int t = 0; t < SEQ/KT; ++t) {
        const int k0 = t * KT;
        __syncthreads();   // prev PV reads done (t=0: pb/band init visible)

        // ---- stage K (transposed) and V (natural) ----
        {
            const float* kp = k + ((size_t)(b*SEQ + k0 + lr))*D_MODEL + h*HEAD_DIM + lc;
            float4 t0 = *(const float4*)(kp + 0);
            float4 t1 = *(const float4*)(kp + 4);
            float4 t2 = *(const float4*)(kp + 8);
            float4 t3 = *(const float4*)(kp + 12);
            float tmp[16] = {t0.x,t0.y,t0.z,t0.w, t1.x,t1.y,t1.z,t1.w,
                             t2.x,t2.y,t2.z,t2.w, t3.x,t3.y,t3.z,t3.w};
            #pragma unroll
            for (int i = 0; i < 16; ++i) KP[(lc+i)*PAD + lr] = tmp[i];

            const float* vp = v + ((size_t)(b*SEQ + k0 + lr))*D_MODEL + h*HEAD_DIM + lc;
            float4 v0 = *(const float4*)(vp + 0);
            float4 v1 = *(const float4*)(vp + 4);
            float4 v2 = *(const float4*)(vp + 8);
            float4 v3 = *(const float4*)(vp + 12);
            *(float4*)&Vs[lr*PAD + lc + 0]  = v0;
            *(float4*)&Vs[lr*PAD + lc + 4]  = v1;
            *(float4*)&Vs[lr*PAD + lc + 8]  = v2;
            *(float4*)&Vs[lr*PAD + lc + 12] = v3;
        }
        __syncthreads();

        // ---- S = Q * K^T (register-tiled) ----
        float acc[4][4] = {};
        #pragma unroll 8
        for (int d = 0; d < HEAD_DIM; ++d) {
            float4 a4 = *(const float4*)&Qs[d*PAD + ty*4];
            float4 b4 = *(const float4*)&KP[d*PAD + tx*4];
            float av[4] = {a4.x,a4.y,a4.z,a4.w};
            float bv[4] = {b4.x,b4.y,b4.z,b4.w};
            #pragma unroll
            for (int i = 0; i < 4; ++i)
                #pragma unroll
                for (int j = 0; j < 4; ++j)
                    acc[i][j] += av[i] * bv[j];
        }

        const int kq = k0 - q0;
        const int mode = (kq <= -128) ? 0 : (kq >= 128 ? 2 : 1);  // 0=left,1=diag,2=right

        // ---- apply pos-bias, scale, mask; row-max partials ----
        float rmax[4] = {-1e30f,-1e30f,-1e30f,-1e30f};
        #pragma unroll
        for (int i = 0; i < 4; ++i) {
            const int ql = ty*4 + i;
            const int qg = q0 + ql;
            const int4 mm = *(const int4*)(mask + ((size_t)b*SEQ + qg)*SEQ + k0 + tx*4);
            const int mk[4] = {mm.x, mm.y, mm.z, mm.w};
            const float pb0  = pb[ql*33 + 0];
            const float pb32 = pb[ql*33 + 32];
            #pragma unroll
            for (int j = 0; j < 4; ++j) {
                float pv;
                if (mode == 0) pv = pb0;
                else if (mode == 2) pv = pb32;
                else {
                    int dk = (k0 + tx*4 + j) - qg;
                    int ii = (dk < -MAX_REL ? -MAX_REL : (dk > MAX_REL ? MAX_REL : dk)) + MAX_REL;
                    pv = pb[ql*33 + ii];
                }
                float s = (acc[i][j] + pv) * inv_scale;
                if (mk[j] == 0) s = -1e30f;
                acc[i][j] = s;
                rmax[i] = fmaxf(rmax[i], s);
            }
        }
        #pragma unroll
        for (int i = 0; i < 4; ++i) red_s[(ty*4+i)*17 + tx] = rmax[i];
        __syncthreads();

        if (tid < QT) {
            float mt = red_s[tid*17];
            #pragma unroll
            for (int xx = 1; xx < 16; ++xx) mt = fmaxf(mt, red_s[tid*17 + xx]);
            const float mo = m_sh[tid];
            const float mn = fmaxf(mo, mt);
            m_sh[tid] = mn;
            al_sh[tid] = __expf(mo - mn);
        }
        __syncthreads();

        // ---- rescale band by alpha (must finish before diag writes) ----
        for (int i2 = tid; i2 < QT*33; i2 += 256) band[i2] *= al_sh[i2/33];
        if (mode == 1) __syncthreads();

        // ---- p = exp(s - m); write P^T to LDS; partial sums; band capture ----
        float rs[4] = {0,0,0,0}, rt[4] = {0,0,0,0};
        #pragma unroll
        for (int i = 0; i < 4; ++i) {
            const int ql = ty*4 + i;
            const int qg = q0 + ql;
            const float mn = m_sh[ql];
            #pragma unroll
            for (int j = 0; j < 4; ++j) {
                const float p = __expf(acc[i][j] - mn);
                rs[i] += p;
                if (mode == 2) rt[i] += p;
                else if (mode == 1) {
                    int dk = (k0 + tx*4 + j) - qg;
                    if (dk > MAX_REL) rt[i] += p;
                    else if (dk >= -MAX_REL) band[ql*33 + dk + MAX_REL] = p;
                }
                KP[(tx*4+j)*PAD + ql] = p;   // P stored [k][q]
            }
        }
        #pragma unroll
        for (int i = 0; i < 4; ++i) {
            const float a = al_sh[ty*4+i];
            #pragma unroll
            for (int j = 0; j < 4; ++j) O[i][j] *= a;
        }
        #pragma unroll
        for (int i = 0; i < 4; ++i) {
            red_s[(ty*4+i)*17 + tx] = rs[i];
            red_t[(ty*4+i)*17 + tx] = rt[i];
        }
        __syncthreads();

        if (tid < QT) {
            float ssum = 0.f, tsum = 0.f;
            #pragma unroll
            for (int xx = 0; xx < 16; ++xx) { ssum += red_s[tid*17+xx]; tsum += red_t[tid*17+xx]; }
            const float a = al_sh[tid];
            l_sh[tid]  = l_sh[tid]  * a + ssum;
            rt_sh[tid] = rt_sh[tid] * a + tsum;
        }

        // ---- O += P * V ----
        #pragma unroll 8
        for (int kk = 0; kk < KT; ++kk) {
            float4 a4 = *(const float4*)&KP[kk*PAD + ty*4];
            float4 b4 = *(const float4*)&Vs[kk*PAD + tx*4];
            float av[4] = {a4.x,a4.y,a4.z,a4.w};
            float bv[4] = {b4.x,b4.y,b4.z,b4.w};
            #pragma unroll
            for (int i = 0; i < 4; ++i)
                #pragma unroll
                for (int j = 0; j < 4; ++j)
                    O[i][j] += av[i] * bv[j];
        }
    }
    __syncthreads();

    // ---- fold tails into band; linv ----
    if (tid < QT) {
        float bs = 0.f;
        #pragma unroll
        for (int j = 0; j < 33; ++j) bs += band[tid*33 + j];
        const float Pl = l_sh[tid] - rt_sh[tid] - bs;
        band[tid*33 + 0]  += Pl;
        band[tid*33 + 32] += rt_sh[tid];
        al_sh[tid] = 1.f / l_sh[tid];
    }
    __syncthreads();

    // ---- weight2 = band @ emb_v; write out ----
    float w2[4][4] = {};
    for (int jj = 0; jj < 33; ++jj) {
        const float4 e4 = *(const float4*)(emb_v + jj*HEAD_DIM + tx*4);
        #pragma unroll
        for (int i = 0; i < 4; ++i) {
            const float bnd = band[(ty*4+i)*33 + jj];
            w2[i][0] += bnd * e4.x;
            w2[i][1] += bnd * e4.y;
            w2[i][2] += bnd * e4.z;
            w2[i][3] += bnd * e4.w;
        }
    }
    #pragma unroll
    for (int i = 0; i < 4; ++i) {
        const int qg = q0 + ty*4 + i;
        const float linv = al_sh[ty*4+i];
        float4 o;
        o.x = (O[i][0] + w2[i][0]) * linv;
        o.y = (O[i][1] + w2[i][1]) * linv;
        o.z = (O[i][2] + w2[i][2]) * linv;
        o.w = (O[i][3] + w2[i][3]) * linv;
        *(float4*)(x + ((size_t)(b*SEQ + qg))*D_MODEL + h*HEAD_DIM + tx*4) = o;
    }
}

extern "C" void kernel_launch(void* const* d_in, const int* in_sizes, int n_in,
                              void* d_out, int out_size, void* d_ws, size_t ws_size,
                              hipStream_t stream) {
    const float* query = (const float*)d_in[0];
    const float* key   = (const float*)d_in[1];
    const float* value = (const float*)d_in[2];
    const int*   mask  = (const int*)d_in[3];
    const float* Wq = (const float*)d_in[4];
    const float* bq = (const float*)d_in[5];
    const float* Wk = (const float*)d_in[6];
    const float* bk = (const float*)d_in[7];
    const float* Wv = (const float*)d_in[8];
    const float* bv = (const float*)d_in[9];
    const float* Wo = (const float*)d_in[10];
    const float* bo = (const float*)d_in[11];
    const float* emb_k = (const float*)d_in[12];
    const float* emb_v = (const float*)d_in[13];
    float* out = (float*)d_out;
    float* ws  = (float*)d_ws;

    const int M = BATCH * SEQ;  // 4096
    float* qb = ws;
    float* kb = qb + (size_t)M * D_MODEL;
    float* vb = kb + (size_t)M * D_MODEL;
    float* xb = vb + (size_t)M * D_MODEL;

    dim3 gB(D_MODEL / BN, M / BM), tB(256);
    gemm_bt_bias<<<gB, tB, 0, stream>>>(query, Wq, bq, qb, M, D_MODEL, D_MODEL);
    gemm_bt_bias<<<gB, tB, 0, stream>>>(key,   Wk, bk, kb, M, D_MODEL, D_MODEL);
    gemm_bt_bias<<<gB, tB, 0, stream>>>(value, Wv, bv, vb, M, D_MODEL, D_MODEL);

    dim3 gA(SEQ/QT, N_HEADS, BATCH);
    attn_flash<<<gA, dim3(256), 0, stream>>>(qb, kb, vb, mask, emb_k, emb_v, xb);

    gemm_bt_bias<<<gB, tB, 0, stream>>>(xb, Wo, bo, out, M, D_MODEL, D_MODEL);
}

// Round 3
// 698.870 us; speedup vs baseline: 7.5625x; 1.3656x over previous
//
#include <hip/hip_runtime.h>
#include <math.h>

#define D_MODEL 1024
#define N_HEADS 16
#define HEAD_DIM 64
#define MAX_REL 16
#define SEQ 1024
#define BATCH 4

typedef _Float16 f16x8 __attribute__((ext_vector_type(8)));
typedef float f32x4 __attribute__((ext_vector_type(4)));

// ---------------- GEMM: C = A * W^T + bias (split-fp16 MFMA) ----------------
// A fp32 [M,K] split exactly into fp16 hi+lo; W fp32 [N,K] truncated to fp16.
// C = Ahi*Whi^T + Alo*Whi^T, fp32 accumulate. Error ~2^-11 rel (W trunc only).
#define GBM 128
#define GBN 128
#define GBK 64
#define LDA 72   // LDS row stride in halves (144 B, 16B-aligned, bank-friendly)

__global__ __launch_bounds__(256) void gemm_bt_bias_f16(
    const float* __restrict__ A,
    const float* __restrict__ W,
    const float* __restrict__ bias,
    float* __restrict__ C, int M, int N, int K)
{
    __shared__ _Float16 Ahi[GBM * LDA];
    __shared__ _Float16 Alo[GBM * LDA];
    __shared__ _Float16 Whi[GBN * LDA];

    const int tid  = threadIdx.x;
    const int m0   = blockIdx.y * GBM;
    const int n0   = blockIdx.x * GBN;
    const int lane = tid & 63;
    const int w    = tid >> 6;
    const int wm   = (w & 1) * 64;
    const int wn   = (w >> 1) * 64;

    // staging coords: 2 threads per row, 32 cols each
    const int srow = tid >> 1;
    const int scb  = (tid & 1) * 32;

    const float* Ab = A + (size_t)(m0 + srow) * K + scb;
    const float* Wb = W + (size_t)(n0 + srow) * K + scb;

    f32x4 acc[4][4];
    #pragma unroll
    for (int i = 0; i < 4; ++i)
        #pragma unroll
        for (int j = 0; j < 4; ++j)
            acc[i][j] = (f32x4){0.f, 0.f, 0.f, 0.f};

    for (int k0 = 0; k0 < K; k0 += GBK) {
        __syncthreads();
        #pragma unroll
        for (int c = 0; c < 32; c += 8) {
            float4 x0 = *(const float4*)(Ab + k0 + c);
            float4 x1 = *(const float4*)(Ab + k0 + c + 4);
            float xs[8] = {x0.x, x0.y, x0.z, x0.w, x1.x, x1.y, x1.z, x1.w};
            f16x8 hi, lo;
            #pragma unroll
            for (int j = 0; j < 8; ++j) {
                _Float16 h = (_Float16)xs[j];
                hi[j] = h;
                lo[j] = (_Float16)(xs[j] - (float)h);
            }
            *(f16x8*)&Ahi[srow * LDA + scb + c] = hi;
            *(f16x8*)&Alo[srow * LDA + scb + c] = lo;

            float4 y0 = *(const float4*)(Wb + k0 + c);
            float4 y1 = *(const float4*)(Wb + k0 + c + 4);
            float ys[8] = {y0.x, y0.y, y0.z, y0.w, y1.x, y1.y, y1.z, y1.w};
            f16x8 wh;
            #pragma unroll
            for (int j = 0; j < 8; ++j) wh[j] = (_Float16)ys[j];
            *(f16x8*)&Whi[srow * LDA + scb + c] = wh;
        }
        __syncthreads();

        #pragma unroll
        for (int ks = 0; ks < GBK; ks += 32) {
            const int kb = ks + (lane >> 4) * 8;
            f16x8 af[4], al[4], bf[4];
            #pragma unroll
            for (int i = 0; i < 4; ++i)
                af[i] = *(const f16x8*)&Ahi[(wm + i*16 + (lane & 15)) * LDA + kb];
            #pragma unroll
            for (int i = 0; i < 4; ++i)
                al[i] = *(const f16x8*)&Alo[(wm + i*16 + (lane & 15)) * LDA + kb];
            #pragma unroll
            for (int j = 0; j < 4; ++j)
                bf[j] = *(const f16x8*)&Whi[(wn + j*16 + (lane & 15)) * LDA + kb];
            #pragma unroll
            for (int i = 0; i < 4; ++i)
                #pragma unroll
                for (int j = 0; j < 4; ++j)
                    acc[i][j] = __builtin_amdgcn_mfma_f32_16x16x32_f16(af[i], bf[j], acc[i][j], 0, 0, 0);
            #pragma unroll
            for (int i = 0; i < 4; ++i)
                #pragma unroll
                for (int j = 0; j < 4; ++j)
                    acc[i][j] = __builtin_amdgcn_mfma_f32_16x16x32_f16(al[i], bf[j], acc[i][j], 0, 0, 0);
        }
    }

    // epilogue: C/D layout col=lane&15, row=(lane>>4)*4+reg
    const int cbase = n0 + wn + (lane & 15);
    const int rbase = m0 + wm + (lane >> 4) * 4;
    #pragma unroll
    for (int j = 0; j < 4; ++j) {
        const int col = cbase + j * 16;
        const float bv = bias[col];
        #pragma unroll
        for (int i = 0; i < 4; ++i) {
            #pragma unroll
            for (int r = 0; r < 4; ++r) {
                const int m = rbase + i * 16 + r;
                C[(size_t)m * N + col] = acc[i][j][r] + bv;
            }
        }
    }
}

// ---------------- Flash attention with relative position ----------------
#define QT 64
#define KT 64
#define PAD 68

__global__ __launch_bounds__(256) void attn_flash(
    const float* __restrict__ q, const float* __restrict__ k,
    const float* __restrict__ v, const int* __restrict__ mask,
    const float* __restrict__ emb_k, const float* __restrict__ emb_v,
    float* __restrict__ x)
{
    __shared__ float Qs[HEAD_DIM * PAD];
    __shared__ float KP[KT * PAD];
    __shared__ float Vs[KT * PAD];
    __shared__ float pb[QT * 33];
    __shared__ float band[QT * 33];
    __shared__ float red_s[QT * 17];
    __shared__ float red_t[QT * 17];
    __shared__ float m_sh[QT], l_sh[QT], rt_sh[QT], al_sh[QT];

    const int qt = blockIdx.x, h = blockIdx.y, b = blockIdx.z;
    const int q0 = qt * QT;
    const int tid = threadIdx.x;
    const int tx = tid & 15, ty = tid >> 4;
    const int lr = tid >> 2;
    const int lc = (tid & 3) * 16;

    {
        const float* qp = q + ((size_t)(b*SEQ + q0 + lr))*D_MODEL + h*HEAD_DIM + lc;
        float4 t0 = *(const float4*)(qp + 0);
        float4 t1 = *(const float4*)(qp + 4);
        float4 t2 = *(const float4*)(qp + 8);
        float4 t3 = *(const float4*)(qp + 12);
        float tmp[16] = {t0.x,t0.y,t0.z,t0.w, t1.x,t1.y,t1.z,t1.w,
                         t2.x,t2.y,t2.z,t2.w, t3.x,t3.y,t3.z,t3.w};
        #pragma unroll
        for (int i = 0; i < 16; ++i) Qs[(lc+i)*PAD + lr] = tmp[i];
    }
    for (int i = tid; i < QT*33; i += 256) band[i] = 0.f;
    if (tid < QT) { m_sh[tid] = -1e30f; l_sh[tid] = 0.f; rt_sh[tid] = 0.f; }
    __syncthreads();

    for (int idx = tid; idx < QT*33; idx += 256) {
        const int qq = idx & 63, j = idx >> 6;
        float s = 0.f;
        #pragma unroll 8
        for (int d = 0; d < HEAD_DIM; ++d) s += Qs[d*PAD + qq] * emb_k[j*HEAD_DIM + d];
        pb[qq*33 + j] = s;
    }

    float O[4][4] = {};
    const float inv_scale = 0.125f;

    for (int t = 0; t < SEQ/KT; ++t) {
        const int k0 = t * KT;
        __syncthreads();

        {
            const float* kp = k + ((size_t)(b*SEQ + k0 + lr))*D_MODEL + h*HEAD_DIM + lc;
            float4 t0 = *(const float4*)(kp + 0);
            float4 t1 = *(const float4*)(kp + 4);
            float4 t2 = *(const float4*)(kp + 8);
            float4 t3 = *(const float4*)(kp + 12);
            float tmp[16] = {t0.x,t0.y,t0.z,t0.w, t1.x,t1.y,t1.z,t1.w,
                             t2.x,t2.y,t2.z,t2.w, t3.x,t3.y,t3.z,t3.w};
            #pragma unroll
            for (int i = 0; i < 16; ++i) KP[(lc+i)*PAD + lr] = tmp[i];

            const float* vp = v + ((size_t)(b*SEQ + k0 + lr))*D_MODEL + h*HEAD_DIM + lc;
            float4 v0 = *(const float4*)(vp + 0);
            float4 v1 = *(const float4*)(vp + 4);
            float4 v2 = *(const float4*)(vp + 8);
            float4 v3 = *(const float4*)(vp + 12);
            *(float4*)&Vs[lr*PAD + lc + 0]  = v0;
            *(float4*)&Vs[lr*PAD + lc + 4]  = v1;
            *(float4*)&Vs[lr*PAD + lc + 8]  = v2;
            *(float4*)&Vs[lr*PAD + lc + 12] = v3;
        }
        __syncthreads();

        float acc[4][4] = {};
        #pragma unroll 8
        for (int d = 0; d < HEAD_DIM; ++d) {
            float4 a4 = *(const float4*)&Qs[d*PAD + ty*4];
            float4 b4 = *(const float4*)&KP[d*PAD + tx*4];
            float av[4] = {a4.x,a4.y,a4.z,a4.w};
            float bv[4] = {b4.x,b4.y,b4.z,b4.w};
            #pragma unroll
            for (int i = 0; i < 4; ++i)
                #pragma unroll
                for (int j = 0; j < 4; ++j)
                    acc[i][j] += av[i] * bv[j];
        }

        const int kq = k0 - q0;
        const int mode = (kq <= -128) ? 0 : (kq >= 128 ? 2 : 1);

        float rmax[4] = {-1e30f,-1e30f,-1e30f,-1e30f};
        #pragma unroll
        for (int i = 0; i < 4; ++i) {
            const int ql = ty*4 + i;
            const int qg = q0 + ql;
            const int4 mm = *(const int4*)(mask + ((size_t)b*SEQ + qg)*SEQ + k0 + tx*4);
            const int mk[4] = {mm.x, mm.y, mm.z, mm.w};
            const float pb0  = pb[ql*33 + 0];
            const float pb32 = pb[ql*33 + 32];
            #pragma unroll
            for (int j = 0; j < 4; ++j) {
                float pv;
                if (mode == 0) pv = pb0;
                else if (mode == 2) pv = pb32;
                else {
                    int dk = (k0 + tx*4 + j) - qg;
                    int ii = (dk < -MAX_REL ? -MAX_REL : (dk > MAX_REL ? MAX_REL : dk)) + MAX_REL;
                    pv = pb[ql*33 + ii];
                }
                float s = (acc[i][j] + pv) * inv_scale;
                if (mk[j] == 0) s = -1e30f;
                acc[i][j] = s;
                rmax[i] = fmaxf(rmax[i], s);
            }
        }
        #pragma unroll
        for (int i = 0; i < 4; ++i) red_s[(ty*4+i)*17 + tx] = rmax[i];
        __syncthreads();

        if (tid < QT) {
            float mt = red_s[tid*17];
            #pragma unroll
            for (int xx = 1; xx < 16; ++xx) mt = fmaxf(mt, red_s[tid*17 + xx]);
            const float mo = m_sh[tid];
            const float mn = fmaxf(mo, mt);
            m_sh[tid] = mn;
            al_sh[tid] = __expf(mo - mn);
        }
        __syncthreads();

        for (int i2 = tid; i2 < QT*33; i2 += 256) band[i2] *= al_sh[i2/33];
        if (mode == 1) __syncthreads();

        float rs[4] = {0,0,0,0}, rt[4] = {0,0,0,0};
        #pragma unroll
        for (int i = 0; i < 4; ++i) {
            const int ql = ty*4 + i;
            const int qg = q0 + ql;
            const float mn = m_sh[ql];
            #pragma unroll
            for (int j = 0; j < 4; ++j) {
                const float p = __expf(acc[i][j] - mn);
                rs[i] += p;
                if (mode == 2) rt[i] += p;
                else if (mode == 1) {
                    int dk = (k0 + tx*4 + j) - qg;
                    if (dk > MAX_REL) rt[i] += p;
                    else if (dk >= -MAX_REL) band[ql*33 + dk + MAX_REL] = p;
                }
                KP[(tx*4+j)*PAD + ql] = p;
            }
        }
        #pragma unroll
        for (int i = 0; i < 4; ++i) {
            const float a = al_sh[ty*4+i];
            #pragma unroll
            for (int j = 0; j < 4; ++j) O[i][j] *= a;
        }
        #pragma unroll
        for (int i = 0; i < 4; ++i) {
            red_s[(ty*4+i)*17 + tx] = rs[i];
            red_t[(ty*4+i)*17 + tx] = rt[i];
        }
        __syncthreads();

        if (tid < QT) {
            float ssum = 0.f, tsum = 0.f;
            #pragma unroll
            for (int xx = 0; xx < 16; ++xx) { ssum += red_s[tid*17+xx]; tsum += red_t[tid*17+xx]; }
            const float a = al_sh[tid];
            l_sh[tid]  = l_sh[tid]  * a + ssum;
            rt_sh[tid] = rt_sh[tid] * a + tsum;
        }

        #pragma unroll 8
        for (int kk = 0; kk < KT; ++kk) {
            float4 a4 = *(const float4*)&KP[kk*PAD + ty*4];
            float4 b4 = *(const float4*)&Vs[kk*PAD + tx*4];
            float av[4] = {a4.x,a4.y,a4.z,a4.w};
            float bv[4] = {b4.x,b4.y,b4.z,b4.w};
            #pragma unroll
            for (int i = 0; i < 4; ++i)
                #pragma unroll
                for (int j = 0; j < 4; ++j)
                    O[i][j] += av[i] * bv[j];
        }
    }
    __syncthreads();

    if (tid < QT) {
        float bs = 0.f;
        #pragma unroll
        for (int j = 0; j < 33; ++j) bs += band[tid*33 + j];
        const float Pl = l_sh[tid] - rt_sh[tid] - bs;
        band[tid*33 + 0]  += Pl;
        band[tid*33 + 32] += rt_sh[tid];
        al_sh[tid] = 1.f / l_sh[tid];
    }
    __syncthreads();

    float w2[4][4] = {};
    for (int jj = 0; jj < 33; ++jj) {
        const float4 e4 = *(const float4*)(emb_v + jj*HEAD_DIM + tx*4);
        #pragma unroll
        for (int i = 0; i < 4; ++i) {
            const float bnd = band[(ty*4+i)*33 + jj];
            w2[i][0] += bnd * e4.x;
            w2[i][1] += bnd * e4.y;
            w2[i][2] += bnd * e4.z;
            w2[i][3] += bnd * e4.w;
        }
    }
    #pragma unroll
    for (int i = 0; i < 4; ++i) {
        const int qg = q0 + ty*4 + i;
        const float linv = al_sh[ty*4+i];
        float4 o;
        o.x = (O[i][0] + w2[i][0]) * linv;
        o.y = (O[i][1] + w2[i][1]) * linv;
        o.z = (O[i][2] + w2[i][2]) * linv;
        o.w = (O[i][3] + w2[i][3]) * linv;
        *(float4*)(x + ((size_t)(b*SEQ + qg))*D_MODEL + h*HEAD_DIM + tx*4) = o;
    }
}

extern "C" void kernel_launch(void* const* d_in, const int* in_sizes, int n_in,
                              void* d_out, int out_size, void* d_ws, size_t ws_size,
                              hipStream_t stream) {
    const float* query = (const float*)d_in[0];
    const float* key   = (const float*)d_in[1];
    const float* value = (const float*)d_in[2];
    const int*   mask  = (const int*)d_in[3];
    const float* Wq = (const float*)d_in[4];
    const float* bq = (const float*)d_in[5];
    const float* Wk = (const float*)d_in[6];
    const float* bk = (const float*)d_in[7];
    const float* Wv = (const float*)d_in[8];
    const float* bv = (const float*)d_in[9];
    const float* Wo = (const float*)d_in[10];
    const float* bo = (const float*)d_in[11];
    const float* emb_k = (const float*)d_in[12];
    const float* emb_v = (const float*)d_in[13];
    float* out = (float*)d_out;
    float* ws  = (float*)d_ws;

    const int M = BATCH * SEQ;  // 4096
    float* qb = ws;
    float* kb = qb + (size_t)M * D_MODEL;
    float* vb = kb + (size_t)M * D_MODEL;
    float* xb = vb + (size_t)M * D_MODEL;

    dim3 gB(D_MODEL / GBN, M / GBM), tB(256);
    gemm_bt_bias_f16<<<gB, tB, 0, stream>>>(query, Wq, bq, qb, M, D_MODEL, D_MODEL);
    gemm_bt_bias_f16<<<gB, tB, 0, stream>>>(key,   Wk, bk, kb, M, D_MODEL, D_MODEL);
    gemm_bt_bias_f16<<<gB, tB, 0, stream>>>(value, Wv, bv, vb, M, D_MODEL, D_MODEL);

    dim3 gA(SEQ/QT, N_HEADS, BATCH);
    attn_flash<<<gA, dim3(256), 0, stream>>>(qb, kb, vb, mask, emb_k, emb_v, xb);

    gemm_bt_bias_f16<<<gB, tB, 0, stream>>>(xb, Wo, bo, out, M, D_MODEL, D_MODEL);
}

// Round 4
// 555.913 us; speedup vs baseline: 9.5073x; 1.2572x over previous
//
#include <hip/hip_runtime.h>
#include <math.h>

#define D_MODEL 1024
#define N_HEADS 16
#define HEAD_DIM 64
#define MAX_REL 16
#define SEQ 1024
#define BATCH 4

typedef _Float16 f16x8 __attribute__((ext_vector_type(8)));
typedef _Float16 f16x2 __attribute__((ext_vector_type(2)));
typedef float f32x4 __attribute__((ext_vector_type(4)));

// ---------------- GEMM: C = A * W^T + bias (split-fp16 MFMA) ----------------
#define GBM 128
#define GBN 128
#define GBK 64
#define LDA 72

__global__ __launch_bounds__(256) void gemm_bt_bias_f16(
    const float* __restrict__ A,
    const float* __restrict__ W,
    const float* __restrict__ bias,
    float* __restrict__ C, int M, int N, int K)
{
    __shared__ _Float16 Ahi[GBM * LDA];
    __shared__ _Float16 Alo[GBM * LDA];
    __shared__ _Float16 Whi[GBN * LDA];

    const int tid  = threadIdx.x;
    const int m0   = blockIdx.y * GBM;
    const int n0   = blockIdx.x * GBN;
    const int lane = tid & 63;
    const int w    = tid >> 6;
    const int wm   = (w & 1) * 64;
    const int wn   = (w >> 1) * 64;

    const int srow = tid >> 1;
    const int scb  = (tid & 1) * 32;

    const float* Ab = A + (size_t)(m0 + srow) * K + scb;
    const float* Wb = W + (size_t)(n0 + srow) * K + scb;

    f32x4 acc[4][4];
    #pragma unroll
    for (int i = 0; i < 4; ++i)
        #pragma unroll
        for (int j = 0; j < 4; ++j)
            acc[i][j] = (f32x4){0.f, 0.f, 0.f, 0.f};

    for (int k0 = 0; k0 < K; k0 += GBK) {
        __syncthreads();
        #pragma unroll
        for (int c = 0; c < 32; c += 8) {
            float4 x0 = *(const float4*)(Ab + k0 + c);
            float4 x1 = *(const float4*)(Ab + k0 + c + 4);
            float xs[8] = {x0.x, x0.y, x0.z, x0.w, x1.x, x1.y, x1.z, x1.w};
            f16x8 hi, lo;
            #pragma unroll
            for (int j = 0; j < 8; ++j) {
                _Float16 hh = (_Float16)xs[j];
                hi[j] = hh;
                lo[j] = (_Float16)(xs[j] - (float)hh);
            }
            *(f16x8*)&Ahi[srow * LDA + scb + c] = hi;
            *(f16x8*)&Alo[srow * LDA + scb + c] = lo;

            float4 y0 = *(const float4*)(Wb + k0 + c);
            float4 y1 = *(const float4*)(Wb + k0 + c + 4);
            float ys[8] = {y0.x, y0.y, y0.z, y0.w, y1.x, y1.y, y1.z, y1.w};
            f16x8 wh;
            #pragma unroll
            for (int j = 0; j < 8; ++j) wh[j] = (_Float16)ys[j];
            *(f16x8*)&Whi[srow * LDA + scb + c] = wh;
        }
        __syncthreads();

        #pragma unroll
        for (int ks = 0; ks < GBK; ks += 32) {
            const int kb = ks + (lane >> 4) * 8;
            f16x8 af[4], al[4], bf[4];
            #pragma unroll
            for (int i = 0; i < 4; ++i)
                af[i] = *(const f16x8*)&Ahi[(wm + i*16 + (lane & 15)) * LDA + kb];
            #pragma unroll
            for (int i = 0; i < 4; ++i)
                al[i] = *(const f16x8*)&Alo[(wm + i*16 + (lane & 15)) * LDA + kb];
            #pragma unroll
            for (int j = 0; j < 4; ++j)
                bf[j] = *(const f16x8*)&Whi[(wn + j*16 + (lane & 15)) * LDA + kb];
            #pragma unroll
            for (int i = 0; i < 4; ++i)
                #pragma unroll
                for (int j = 0; j < 4; ++j)
                    acc[i][j] = __builtin_amdgcn_mfma_f32_16x16x32_f16(af[i], bf[j], acc[i][j], 0, 0, 0);
            #pragma unroll
            for (int i = 0; i < 4; ++i)
                #pragma unroll
                for (int j = 0; j < 4; ++j)
                    acc[i][j] = __builtin_amdgcn_mfma_f32_16x16x32_f16(al[i], bf[j], acc[i][j], 0, 0, 0);
        }
    }

    const int cbase = n0 + wn + (lane & 15);
    const int rbase = m0 + wm + (lane >> 4) * 4;
    #pragma unroll
    for (int j = 0; j < 4; ++j) {
        const int col = cbase + j * 16;
        const float bv = bias[col];
        #pragma unroll
        for (int i = 0; i < 4; ++i) {
            #pragma unroll
            for (int r = 0; r < 4; ++r) {
                const int m = rbase + i * 16 + r;
                C[(size_t)m * N + col] = acc[i][j][r] + bv;
            }
        }
    }
}

// ---------------- Flash attention, MFMA (fp16 split) ----------------
// Block = 64 queries x (b,h), 256 threads = 4 waves. Per 64-key tile:
// S = (Qhi+Qlo)*Ks^T via mfma_16x16x32_f16 (wave w owns q rows w*16..+15),
// softmax bookkeeping in MFMA C/D layout, P->LDS fp16, O += P*V via MFMA.
// V staged k-major with XOR swizzle (k8 ^= (d>>3)&7) for conflict-free stores.
#define QT 64
#define KT 64
#define SP 72   // fp16 LDS row stride (144 B, 16B-aligned)

__global__ __launch_bounds__(256) void attn_flash_mfma(
    const float* __restrict__ q, const float* __restrict__ k,
    const float* __restrict__ v, const int* __restrict__ mask,
    const float* __restrict__ emb_k, const float* __restrict__ emb_v,
    float* __restrict__ x)
{
    __shared__ _Float16 Qhi[QT * SP];
    __shared__ _Float16 Qlo[QT * SP];
    __shared__ _Float16 Ks[KT * SP];        // [k][d]
    __shared__ _Float16 Vt[HEAD_DIM * SP];  // [d][k] swizzled
    __shared__ _Float16 Ps[QT * SP];        // [q][k]
    __shared__ float pb[QT * 33];
    __shared__ float band[QT * 33];
    __shared__ float red_s[QT * 17];
    __shared__ float red_t[QT * 17];
    __shared__ float m_sh[QT], l_sh[QT], rt_sh[QT], al_sh[QT];

    const int qt = blockIdx.x, h = blockIdx.y, b = blockIdx.z;
    const int q0 = qt * QT;
    const int tid = threadIdx.x;
    const int lane = tid & 63;
    const int w = tid >> 6;
    const int quad = lane >> 4;
    const int l16 = lane & 15;
    const int qrow = w * 16 + quad * 4;

    const int sr = tid >> 2;         // staging row 0..63
    const int sc = (tid & 3) * 16;   // staging col base

    // ---- stage Q split hi/lo ----
    {
        const float* qp = q + ((size_t)(b*SEQ + q0 + sr))*D_MODEL + h*HEAD_DIM + sc;
        #pragma unroll
        for (int g = 0; g < 2; ++g) {
            float4 x0 = *(const float4*)(qp + g*8);
            float4 x1 = *(const float4*)(qp + g*8 + 4);
            float xs[8] = {x0.x,x0.y,x0.z,x0.w, x1.x,x1.y,x1.z,x1.w};
            f16x8 hi, lo;
            #pragma unroll
            for (int j = 0; j < 8; ++j) {
                _Float16 hh = (_Float16)xs[j];
                hi[j] = hh;
                lo[j] = (_Float16)(xs[j] - (float)hh);
            }
            *(f16x8*)&Qhi[sr*SP + sc + g*8] = hi;
            *(f16x8*)&Qlo[sr*SP + sc + g*8] = lo;
        }
    }
    for (int i = tid; i < QT*33; i += 256) band[i] = 0.f;
    if (tid < QT) { m_sh[tid] = -1e30f; l_sh[tid] = 0.f; rt_sh[tid] = 0.f; }
    __syncthreads();

    // ---- pb[q][j] = q . emb_k[j] (fp32 via hi+lo) ----
    for (int idx = tid; idx < QT*33; idx += 256) {
        const int qq = idx & 63, j = idx >> 6;
        float s = 0.f;
        #pragma unroll 8
        for (int d = 0; d < HEAD_DIM; ++d)
            s += ((float)Qhi[qq*SP + d] + (float)Qlo[qq*SP + d]) * emb_k[j*HEAD_DIM + d];
        pb[qq*33 + j] = s;
    }

    f32x4 accO[4];
    #pragma unroll
    for (int dt = 0; dt < 4; ++dt) accO[dt] = (f32x4){0.f,0.f,0.f,0.f};

    const float inv_scale = 0.125f;

    for (int t = 0; t < SEQ/KT; ++t) {
        const int k0 = t * KT;
        __syncthreads();   // Ks/Vt reuse safe; tile-0: pb/band init visible

        // ---- stage K (trunc fp16, [k][d]) ----
        {
            const float* kp = k + ((size_t)(b*SEQ + k0 + sr))*D_MODEL + h*HEAD_DIM + sc;
            #pragma unroll
            for (int g = 0; g < 2; ++g) {
                float4 x0 = *(const float4*)(kp + g*8);
                float4 x1 = *(const float4*)(kp + g*8 + 4);
                float xs[8] = {x0.x,x0.y,x0.z,x0.w, x1.x,x1.y,x1.z,x1.w};
                f16x8 hh;
                #pragma unroll
                for (int j = 0; j < 8; ++j) hh[j] = (_Float16)xs[j];
                *(f16x8*)&Ks[sr*SP + sc + g*8] = hh;
            }
        }
        // ---- stage V transposed+swizzled: Vt[d][(k8^xd)*8 + k&7] ----
        {
            const int vk = (tid & 31) * 2;
            const int vd = (tid >> 5) * 8;
            const float* vp = v + ((size_t)(b*SEQ + k0 + vk))*D_MODEL + h*HEAD_DIM + vd;
            float4 a0 = *(const float4*)(vp + 0);
            float4 a1 = *(const float4*)(vp + 4);
            float4 b0 = *(const float4*)(vp + D_MODEL + 0);
            float4 b1 = *(const float4*)(vp + D_MODEL + 4);
            float va[8] = {a0.x,a0.y,a0.z,a0.w, a1.x,a1.y,a1.z,a1.w};
            float vb[8] = {b0.x,b0.y,b0.z,b0.w, b1.x,b1.y,b1.z,b1.w};
            const int k8 = vk >> 3, klo = vk & 7;
            #pragma unroll
            for (int i = 0; i < 8; ++i) {
                const int d = vd + i;
                const int xd = (d >> 3) & 7;
                f16x2 pr;
                pr[0] = (_Float16)va[i];
                pr[1] = (_Float16)vb[i];
                *(f16x2*)&Vt[d*SP + ((k8 ^ xd) << 3) + klo] = pr;
            }
        }
        __syncthreads();

        // ---- S = Q K^T via MFMA ----
        f32x4 accS[4];
        #pragma unroll
        for (int jt = 0; jt < 4; ++jt) accS[jt] = (f32x4){0.f,0.f,0.f,0.f};
        #pragma unroll
        for (int kstep = 0; kstep < 2; ++kstep) {
            const int ko = kstep*32 + quad*8;
            f16x8 ah = *(const f16x8*)&Qhi[(w*16 + l16)*SP + ko];
            f16x8 al = *(const f16x8*)&Qlo[(w*16 + l16)*SP + ko];
            f16x8 bf[4];
            #pragma unroll
            for (int jt = 0; jt < 4; ++jt)
                bf[jt] = *(const f16x8*)&Ks[(jt*16 + l16)*SP + ko];
            #pragma unroll
            for (int jt = 0; jt < 4; ++jt)
                accS[jt] = __builtin_amdgcn_mfma_f32_16x16x32_f16(ah, bf[jt], accS[jt], 0, 0, 0);
            #pragma unroll
            for (int jt = 0; jt < 4; ++jt)
                accS[jt] = __builtin_amdgcn_mfma_f32_16x16x32_f16(al, bf[jt], accS[jt], 0, 0, 0);
        }

        const int kq = k0 - q0;
        const int mode = (kq <= -128) ? 0 : (kq >= 128 ? 2 : 1);

        // ---- bias + scale + mask + row-max partials ----
        // value at (q = qrow + r, k = jt*16 + l16)
        float rmax[4] = {-1e30f,-1e30f,-1e30f,-1e30f};
        const int* mbase = mask + ((size_t)b*SEQ + q0 + qrow)*SEQ + k0;
        #pragma unroll
        for (int jt = 0; jt < 4; ++jt) {
            const int kl = jt*16 + l16;
            #pragma unroll
            for (int r = 0; r < 4; ++r) {
                const int ql = qrow + r;
                const int qg = q0 + ql;
                float pv;
                if (mode == 0) pv = pb[ql*33 + 0];
                else if (mode == 2) pv = pb[ql*33 + 32];
                else {
                    int dk = (k0 + kl) - qg;
                    int ii = (dk < -MAX_REL ? -MAX_REL : (dk > MAX_REL ? MAX_REL : dk)) + MAX_REL;
                    pv = pb[ql*33 + ii];
                }
                float s = (accS[jt][r] + pv) * inv_scale;
                if (mbase[(size_t)r*SEQ + kl] == 0) s = -1e30f;
                accS[jt][r] = s;
                rmax[r] = fmaxf(rmax[r], s);
            }
        }
        #pragma unroll
        for (int r = 0; r < 4; ++r) red_s[(qrow + r)*17 + l16] = rmax[r];
        __syncthreads();

        if (tid < QT) {
            float mt = red_s[tid*17];
            #pragma unroll
            for (int xx = 1; xx < 16; ++xx) mt = fmaxf(mt, red_s[tid*17 + xx]);
            const float mo = m_sh[tid];
            const float mn = fmaxf(mo, mt);
            m_sh[tid] = mn;
            al_sh[tid] = __expf(mo - mn);
        }
        __syncthreads();

        for (int i2 = tid; i2 < QT*33; i2 += 256) band[i2] *= al_sh[i2/33];
        if (mode == 1) __syncthreads();

        // ---- p = exp(s-m); Ps fp16; partial sums; band capture ----
        float mn[4], alf[4];
        #pragma unroll
        for (int r = 0; r < 4; ++r) { mn[r] = m_sh[qrow + r]; alf[r] = al_sh[qrow + r]; }
        float rs[4] = {0,0,0,0}, rt[4] = {0,0,0,0};
        #pragma unroll
        for (int jt = 0; jt < 4; ++jt) {
            const int kl = jt*16 + l16;
            #pragma unroll
            for (int r = 0; r < 4; ++r) {
                const int ql = qrow + r;
                const float p = __expf(accS[jt][r] - mn[r]);
                rs[r] += p;
                if (mode == 2) rt[r] += p;
                else if (mode == 1) {
                    int dk = (k0 + kl) - (q0 + ql);
                    if (dk > MAX_REL) rt[r] += p;
                    else if (dk >= -MAX_REL) band[ql*33 + dk + MAX_REL] = p;
                }
                Ps[ql*SP + kl] = (_Float16)p;
            }
        }
        #pragma unroll
        for (int dt = 0; dt < 4; ++dt)
            #pragma unroll
            for (int r = 0; r < 4; ++r) accO[dt][r] *= alf[r];
        #pragma unroll
        for (int r = 0; r < 4; ++r) {
            red_s[(qrow + r)*17 + l16] = rs[r];
            red_t[(qrow + r)*17 + l16] = rt[r];
        }
        __syncthreads();

        if (tid < QT) {
            float ssum = 0.f, tsum = 0.f;
            #pragma unroll
            for (int xx = 0; xx < 16; ++xx) { ssum += red_s[tid*17+xx]; tsum += red_t[tid*17+xx]; }
            const float a = al_sh[tid];
            l_sh[tid]  = l_sh[tid]  * a + ssum;
            rt_sh[tid] = rt_sh[tid] * a + tsum;
        }

        // ---- O += P * V via MFMA (Ps rows owned by this wave) ----
        #pragma unroll
        for (int kstep = 0; kstep < 2; ++kstep) {
            const int ko = kstep*32 + quad*8;
            const int k8n = kstep*4 + quad;
            f16x8 pf = *(const f16x8*)&Ps[(w*16 + l16)*SP + ko];
            #pragma unroll
            for (int dt = 0; dt < 4; ++dt) {
                const int d = dt*16 + l16;
                const int xd = (d >> 3) & 7;
                f16x8 vf = *(const f16x8*)&Vt[d*SP + ((k8n ^ xd) << 3)];
                accO[dt] = __builtin_amdgcn_mfma_f32_16x16x32_f16(pf, vf, accO[dt], 0, 0, 0);
            }
        }
    }
    __syncthreads();

    // ---- fold tails; linv ----
    if (tid < QT) {
        float bs = 0.f;
        #pragma unroll
        for (int j = 0; j < 33; ++j) bs += band[tid*33 + j];
        const float Pl = l_sh[tid] - rt_sh[tid] - bs;
        band[tid*33 + 0]  += Pl;
        band[tid*33 + 32] += rt_sh[tid];
        al_sh[tid] = 1.f / l_sh[tid];
    }
    __syncthreads();

    // ---- weight2 = band @ emb_v; write out (C/D layout) ----
    float w2[4][4] = {};
    for (int jj = 0; jj < 33; ++jj) {
        float ev[4];
        #pragma unroll
        for (int dt = 0; dt < 4; ++dt) ev[dt] = emb_v[jj*HEAD_DIM + dt*16 + l16];
        #pragma unroll
        for (int r = 0; r < 4; ++r) {
            const float bnd = band[(qrow + r)*33 + jj];
            #pragma unroll
            for (int dt = 0; dt < 4; ++dt) w2[dt][r] += bnd * ev[dt];
        }
    }
    #pragma unroll
    for (int r = 0; r < 4; ++r) {
        const int qg = q0 + qrow + r;
        const float linv = al_sh[qrow + r];
        #pragma unroll
        for (int dt = 0; dt < 4; ++dt) {
            x[((size_t)(b*SEQ + qg))*D_MODEL + h*HEAD_DIM + dt*16 + l16] =
                (accO[dt][r] + w2[dt][r]) * linv;
        }
    }
}

extern "C" void kernel_launch(void* const* d_in, const int* in_sizes, int n_in,
                              void* d_out, int out_size, void* d_ws, size_t ws_size,
                              hipStream_t stream) {
    const float* query = (const float*)d_in[0];
    const float* key   = (const float*)d_in[1];
    const float* value = (const float*)d_in[2];
    const int*   mask  = (const int*)d_in[3];
    const float* Wq = (const float*)d_in[4];
    const float* bq = (const float*)d_in[5];
    const float* Wk = (const float*)d_in[6];
    const float* bk = (const float*)d_in[7];
    const float* Wv = (const float*)d_in[8];
    const float* bv = (const float*)d_in[9];
    const float* Wo = (const float*)d_in[10];
    const float* bo = (const float*)d_in[11];
    const float* emb_k = (const float*)d_in[12];
    const float* emb_v = (const float*)d_in[13];
    float* out = (float*)d_out;
    float* ws  = (float*)d_ws;

    const int M = BATCH * SEQ;  // 4096
    float* qb = ws;
    float* kb = qb + (size_t)M * D_MODEL;
    float* vb = kb + (size_t)M * D_MODEL;
    float* xb = vb + (size_t)M * D_MODEL;

    dim3 gB(D_MODEL / GBN, M / GBM), tB(256);
    gemm_bt_bias_f16<<<gB, tB, 0, stream>>>(query, Wq, bq, qb, M, D_MODEL, D_MODEL);
    gemm_bt_bias_f16<<<gB, tB, 0, stream>>>(key,   Wk, bk, kb, M, D_MODEL, D_MODEL);
    gemm_bt_bias_f16<<<gB, tB, 0, stream>>>(value, Wv, bv, vb, M, D_MODEL, D_MODEL);

    dim3 gA(SEQ/QT, N_HEADS, BATCH);
    attn_flash_mfma<<<gA, dim3(256), 0, stream>>>(qb, kb, vb, mask, emb_k, emb_v, xb);

    gemm_bt_bias_f16<<<gB, tB, 0, stream>>>(xb, Wo, bo, out, M, D_MODEL, D_MODEL);
}

// Round 6
// 429.252 us; speedup vs baseline: 12.3126x; 1.2951x over previous
//
#include <hip/hip_runtime.h>
#include <math.h>

#define D_MODEL 1024
#define N_HEADS 16
#define HEAD_DIM 64
#define MAX_REL 16
#define SEQ 1024
#define BATCH 4

typedef _Float16 f16x8 __attribute__((ext_vector_type(8)));
typedef _Float16 f16x2 __attribute__((ext_vector_type(2)));
typedef float f32x4 __attribute__((ext_vector_type(4)));

// ---------------- GEMM: C = A * W^T + bias (split-fp16 MFMA) ----------------
// 64x128 tile, 256 thr = 4 waves (2m x 2n), ~37 KB LDS -> ~4 blocks/CU.
// z-dim selects one of up to 3 (A,W,bias,C) sets (fused QKV).
#define GBM 64
#define GBN 128
#define GBK 64
#define LDA 72

__global__ __launch_bounds__(256) void gemm_bt_bias_f16v2(
    const float* A0, const float* A1, const float* A2,
    const float* W0, const float* W1, const float* W2,
    const float* b0, const float* b1, const float* b2,
    float* C0, float* C1, float* C2, int M, int N, int K)
{
    __shared__ _Float16 Ahi[GBM * LDA];
    __shared__ _Float16 Alo[GBM * LDA];
    __shared__ _Float16 Whi[GBN * LDA];

    const int z = blockIdx.z;
    const float* A = (z == 0) ? A0 : (z == 1) ? A1 : A2;
    const float* W = (z == 0) ? W0 : (z == 1) ? W1 : W2;
    const float* bias = (z == 0) ? b0 : (z == 1) ? b1 : b2;
    float* C = (z == 0) ? C0 : (z == 1) ? C1 : C2;

    const int tid  = threadIdx.x;
    const int m0   = blockIdx.y * GBM;
    const int n0   = blockIdx.x * GBN;
    const int lane = tid & 63;
    const int w    = tid >> 6;
    const int quad = lane >> 4;
    const int l16  = lane & 15;
    const int wm   = (w & 1) * 32;
    const int wn   = (w >> 1) * 64;

    const int sra = tid >> 2, sca = (tid & 3) * 16;   // A: 64 rows x 16 cols
    const int srw = tid >> 1, scw = (tid & 1) * 32;   // W: 128 rows x 32 cols

    const float* Ab = A + (size_t)(m0 + sra) * K + sca;
    const float* Wb = W + (size_t)(n0 + srw) * K + scw;

    f32x4 acc[2][4];
    #pragma unroll
    for (int i = 0; i < 2; ++i)
        #pragma unroll
        for (int j = 0; j < 4; ++j)
            acc[i][j] = (f32x4){0.f, 0.f, 0.f, 0.f};

    for (int k0 = 0; k0 < K; k0 += GBK) {
        __syncthreads();
        #pragma unroll
        for (int c = 0; c < 16; c += 8) {
            float4 x0 = *(const float4*)(Ab + k0 + c);
            float4 x1 = *(const float4*)(Ab + k0 + c + 4);
            float xs[8] = {x0.x, x0.y, x0.z, x0.w, x1.x, x1.y, x1.z, x1.w};
            f16x8 hi, lo;
            #pragma unroll
            for (int j = 0; j < 8; ++j) {
                _Float16 hh = (_Float16)xs[j];
                hi[j] = hh;
                lo[j] = (_Float16)(xs[j] - (float)hh);
            }
            *(f16x8*)&Ahi[sra * LDA + sca + c] = hi;
            *(f16x8*)&Alo[sra * LDA + sca + c] = lo;
        }
        #pragma unroll
        for (int c = 0; c < 32; c += 8) {
            float4 y0 = *(const float4*)(Wb + k0 + c);
            float4 y1 = *(const float4*)(Wb + k0 + c + 4);
            float ys[8] = {y0.x, y0.y, y0.z, y0.w, y1.x, y1.y, y1.z, y1.w};
            f16x8 wh;
            #pragma unroll
            for (int j = 0; j < 8; ++j) wh[j] = (_Float16)ys[j];
            *(f16x8*)&Whi[srw * LDA + scw + c] = wh;
        }
        __syncthreads();

        #pragma unroll
        for (int ks = 0; ks < GBK; ks += 32) {
            const int kb = ks + quad * 8;
            f16x8 af[2], al[2], bf[4];
            #pragma unroll
            for (int i = 0; i < 2; ++i)
                af[i] = *(const f16x8*)&Ahi[(wm + i*16 + l16) * LDA + kb];
            #pragma unroll
            for (int i = 0; i < 2; ++i)
                al[i] = *(const f16x8*)&Alo[(wm + i*16 + l16) * LDA + kb];
            #pragma unroll
            for (int j = 0; j < 4; ++j)
                bf[j] = *(const f16x8*)&Whi[(wn + j*16 + l16) * LDA + kb];
            #pragma unroll
            for (int i = 0; i < 2; ++i)
                #pragma unroll
                for (int j = 0; j < 4; ++j)
                    acc[i][j] = __builtin_amdgcn_mfma_f32_16x16x32_f16(af[i], bf[j], acc[i][j], 0, 0, 0);
            #pragma unroll
            for (int i = 0; i < 2; ++i)
                #pragma unroll
                for (int j = 0; j < 4; ++j)
                    acc[i][j] = __builtin_amdgcn_mfma_f32_16x16x32_f16(al[i], bf[j], acc[i][j], 0, 0, 0);
        }
    }

    const int cbase = n0 + wn + l16;
    const int rbase = m0 + wm + quad * 4;
    #pragma unroll
    for (int j = 0; j < 4; ++j) {
        const int col = cbase + j * 16;
        const float bv = bias[col];
        #pragma unroll
        for (int i = 0; i < 2; ++i) {
            #pragma unroll
            for (int r = 0; r < 4; ++r) {
                const int m = rbase + i * 16 + r;
                C[(size_t)m * N + col] = acc[i][j][r] + bv;
            }
        }
    }
}

// ---------------- Flash attention, MFMA, register-state online softmax ------
// Block = 64 q x (b,h), 4 waves; wave w owns q rows w*16..w*16+15 exclusively.
// m/l/rtail in registers (shfl_xor reductions over the 16 l16 lanes).
// band stores RAW LOGITS (no per-tile rescale); single exp at epilogue.
// K/V/mask register-prefetched, ping-pong LDS: ONE barrier per tile.
// pb = Q@emb_k^T and w2 = band_p@emb_v via MFMA (emb tables staged fp16).
#define QT 64
#define KT 64
#define SP 72

__global__ __launch_bounds__(256) void attn_flash_mfma2(
    const float* __restrict__ q, const float* __restrict__ kg,
    const float* __restrict__ v, const int* __restrict__ mask,
    const float* __restrict__ emb_k, const float* __restrict__ emb_v,
    float* __restrict__ x)
{
    __shared__ _Float16 Ks[2][KT * SP];
    __shared__ _Float16 Vt[2][HEAD_DIM * SP];
    __shared__ _Float16 Ps[QT * SP];
    __shared__ _Float16 EvT[HEAD_DIM * SP];   // emb_v^T [d][j], fp16, zero-padded
    __shared__ float pb[QT * 33];
    __shared__ float band[QT * 33];           // raw logits

    const int qt = blockIdx.x, h = blockIdx.y, b = blockIdx.z;
    const int q0 = qt * QT;
    const int tid = threadIdx.x;
    const int lane = tid & 63;
    const int w = tid >> 6;
    const int quad = lane >> 4;
    const int l16 = lane & 15;
    const int qrow = w * 16 + quad * 4;

    const int sr = tid >> 2, sc = (tid & 3) * 16;   // K staging: row, col base
    const int vk = (tid & 31) * 2, vd = (tid >> 5) * 8;  // V staging
    const int k8 = vk >> 3, klo = vk & 7;

    // ---- Q fragments -> registers (hi/lo split) ----
    f16x8 qhi[2], qlo[2];
    {
        const float* qp = q + ((size_t)(b*SEQ + q0 + w*16 + l16))*D_MODEL + h*HEAD_DIM;
        #pragma unroll
        for (int ks2 = 0; ks2 < 2; ++ks2) {
            const float* p = qp + ks2*32 + quad*8;
            float4 x0 = *(const float4*)(p);
            float4 x1 = *(const float4*)(p + 4);
            float xs[8] = {x0.x,x0.y,x0.z,x0.w, x1.x,x1.y,x1.z,x1.w};
            #pragma unroll
            for (int j = 0; j < 8; ++j) {
                _Float16 hh = (_Float16)xs[j];
                qhi[ks2][j] = hh;
                qlo[ks2][j] = (_Float16)(xs[j] - (float)hh);
            }
        }
    }

    // ---- stage emb_k (48 rows, zero-pad) into Ks[0]; emb_v^T into EvT ----
    if (sr < 48) {
        #pragma unroll
        for (int c = 0; c < 16; ++c) {
            float val = (sr < 33) ? emb_k[sr*HEAD_DIM + sc + c] : 0.f;
            Ks[0][sr*SP + sc + c] = (_Float16)val;
        }
    }
    for (int idx = tid; idx < 64*64; idx += 256) {
        const int d = idx >> 6, j = idx & 63;
        float val = (j < 33) ? emb_v[j*HEAD_DIM + d] : 0.f;
        EvT[d*SP + j] = (_Float16)val;
    }
    for (int i = tid; i < QT*33; i += 256) band[i] = -1e30f;
    __syncthreads();

    // ---- pb = Q @ emb_k^T via MFMA ----
    f32x4 accP[3];
    #pragma unroll
    for (int jt = 0; jt < 3; ++jt) accP[jt] = (f32x4){0.f,0.f,0.f,0.f};
    #pragma unroll
    for (int ks2 = 0; ks2 < 2; ++ks2) {
        const int ko = ks2*32 + quad*8;
        f16x8 bf[3];
        #pragma unroll
        for (int jt = 0; jt < 3; ++jt)
            bf[jt] = *(const f16x8*)&Ks[0][(jt*16 + l16)*SP + ko];
        #pragma unroll
        for (int jt = 0; jt < 3; ++jt) {
            accP[jt] = __builtin_amdgcn_mfma_f32_16x16x32_f16(qhi[ks2], bf[jt], accP[jt], 0, 0, 0);
            accP[jt] = __builtin_amdgcn_mfma_f32_16x16x32_f16(qlo[ks2], bf[jt], accP[jt], 0, 0, 0);
        }
    }
    #pragma unroll
    for (int jt = 0; jt < 3; ++jt) {
        const int j = jt*16 + l16;
        if (j < 33) {
            #pragma unroll
            for (int r = 0; r < 4; ++r) pb[(qrow + r)*33 + j] = accP[jt][r];
        }
    }
    float pb0r[4], pb32r[4];
    #pragma unroll
    for (int r = 0; r < 4; ++r) {
        pb0r[r]  = __shfl(accP[0][r], quad * 16);
        pb32r[r] = __shfl(accP[2][r], quad * 16);
    }
    __syncthreads();   // pb visible; emb_k reads done before Ks[0] reuse

    // ---- softmax state in registers ----
    float m_r[4], l_r[4], rt_r[4];
    #pragma unroll
    for (int r = 0; r < 4; ++r) { m_r[r] = -1e30f; l_r[r] = 0.f; rt_r[r] = 0.f; }
    f32x4 accO[4];
    #pragma unroll
    for (int dt = 0; dt < 4; ++dt) accO[dt] = (f32x4){0.f,0.f,0.f,0.f};

    // prefetch registers
    float ka[16], va8[8], vb8[8];

    // ---- prologue: stage tile 0 ----
    {
        const float* kp = kg + ((size_t)(b*SEQ + 0 + sr))*D_MODEL + h*HEAD_DIM + sc;
        #pragma unroll
        for (int g = 0; g < 2; ++g) {
            float4 x0 = *(const float4*)(kp + g*8);
            float4 x1 = *(const float4*)(kp + g*8 + 4);
            ka[g*8+0]=x0.x; ka[g*8+1]=x0.y; ka[g*8+2]=x0.z; ka[g*8+3]=x0.w;
            ka[g*8+4]=x1.x; ka[g*8+5]=x1.y; ka[g*8+6]=x1.z; ka[g*8+7]=x1.w;
        }
        const float* vp = v + ((size_t)(b*SEQ + 0 + vk))*D_MODEL + h*HEAD_DIM + vd;
        float4 a0 = *(const float4*)(vp + 0);
        float4 a1 = *(const float4*)(vp + 4);
        float4 c0 = *(const float4*)(vp + D_MODEL + 0);
        float4 c1 = *(const float4*)(vp + D_MODEL + 4);
        va8[0]=a0.x; va8[1]=a0.y; va8[2]=a0.z; va8[3]=a0.w;
        va8[4]=a1.x; va8[5]=a1.y; va8[6]=a1.z; va8[7]=a1.w;
        vb8[0]=c0.x; vb8[1]=c0.y; vb8[2]=c0.z; vb8[3]=c0.w;
        vb8[4]=c1.x; vb8[5]=c1.y; vb8[6]=c1.z; vb8[7]=c1.w;

        // write buf 0
        #pragma unroll
        for (int g = 0; g < 2; ++g) {
            f16x8 hh;
            #pragma unroll
            for (int j = 0; j < 8; ++j) hh[j] = (_Float16)ka[g*8+j];
            *(f16x8*)&Ks[0][sr*SP + sc + g*8] = hh;
        }
        #pragma unroll
        for (int i = 0; i < 8; ++i) {
            const int d = vd + i;
            const int xd = (d >> 3) & 7;
            f16x2 pr; pr[0] = (_Float16)va8[i]; pr[1] = (_Float16)vb8[i];
            *(f16x2*)&Vt[0][d*SP + ((k8 ^ xd) << 3) + klo] = pr;
        }
    }
    __syncthreads();

    const float inv_scale = 0.125f;

    for (int t = 0; t < SEQ/KT; ++t) {
        const int buf = t & 1;
        const int k0 = t * KT;

        // ---- prefetch tile t+1 (global -> regs) ----
        if (t + 1 < SEQ/KT) {
            const int kn = k0 + KT;
            const float* kp = kg + ((size_t)(b*SEQ + kn + sr))*D_MODEL + h*HEAD_DIM + sc;
            #pragma unroll
            for (int g = 0; g < 2; ++g) {
                float4 x0 = *(const float4*)(kp + g*8);
                float4 x1 = *(const float4*)(kp + g*8 + 4);
                ka[g*8+0]=x0.x; ka[g*8+1]=x0.y; ka[g*8+2]=x0.z; ka[g*8+3]=x0.w;
                ka[g*8+4]=x1.x; ka[g*8+5]=x1.y; ka[g*8+6]=x1.z; ka[g*8+7]=x1.w;
            }
            const float* vp = v + ((size_t)(b*SEQ + kn + vk))*D_MODEL + h*HEAD_DIM + vd;
            float4 a0 = *(const float4*)(vp + 0);
            float4 a1 = *(const float4*)(vp + 4);
            float4 c0 = *(const float4*)(vp + D_MODEL + 0);
            float4 c1 = *(const float4*)(vp + D_MODEL + 4);
            va8[0]=a0.x; va8[1]=a0.y; va8[2]=a0.z; va8[3]=a0.w;
            va8[4]=a1.x; va8[5]=a1.y; va8[6]=a1.z; va8[7]=a1.w;
            vb8[0]=c0.x; vb8[1]=c0.y; vb8[2]=c0.z; vb8[3]=c0.w;
            vb8[4]=c1.x; vb8[5]=c1.y; vb8[6]=c1.z; vb8[7]=c1.w;
        }

        // ---- mask loads for this tile ----
        int mr[4][4];
        {
            const int* mb = mask + ((size_t)(b*SEQ + q0 + qrow))*SEQ + k0;
            #pragma unroll
            for (int jt = 0; jt < 4; ++jt)
                #pragma unroll
                for (int r = 0; r < 4; ++r)
                    mr[jt][r] = mb[(size_t)r*SEQ + jt*16 + l16];
        }

        // ---- S = Q K^T ----
        f32x4 accS[4];
        #pragma unroll
        for (int jt = 0; jt < 4; ++jt) accS[jt] = (f32x4){0.f,0.f,0.f,0.f};
        #pragma unroll
        for (int ks2 = 0; ks2 < 2; ++ks2) {
            const int ko = ks2*32 + quad*8;
            f16x8 bf[4];
            #pragma unroll
            for (int jt = 0; jt < 4; ++jt)
                bf[jt] = *(const f16x8*)&Ks[buf][(jt*16 + l16)*SP + ko];
            #pragma unroll
            for (int jt = 0; jt < 4; ++jt)
                accS[jt] = __builtin_amdgcn_mfma_f32_16x16x32_f16(qhi[ks2], bf[jt], accS[jt], 0, 0, 0);
            #pragma unroll
            for (int jt = 0; jt < 4; ++jt)
                accS[jt] = __builtin_amdgcn_mfma_f32_16x16x32_f16(qlo[ks2], bf[jt], accS[jt], 0, 0, 0);
        }

        const int kq = k0 - q0;
        const int mode = (kq <= -128) ? 0 : (kq >= 128 ? 2 : 1);

        // ---- bias + scale + mask; row-max (regs + shfl) ----
        float rmax[4] = {-1e30f,-1e30f,-1e30f,-1e30f};
        #pragma unroll
        for (int jt = 0; jt < 4; ++jt) {
            const int kl = jt*16 + l16;
            #pragma unroll
            for (int r = 0; r < 4; ++r) {
                float pv;
                if (mode == 0) pv = pb0r[r];
                else if (mode == 2) pv = pb32r[r];
                else {
                    int dk = (k0 + kl) - (q0 + qrow + r);
                    int ii = (dk < -MAX_REL ? -MAX_REL : (dk > MAX_REL ? MAX_REL : dk)) + MAX_REL;
                    pv = pb[(qrow + r)*33 + ii];
                }
                float s = (accS[jt][r] + pv) * inv_scale;
                s = mr[jt][r] ? s : -1e30f;
                accS[jt][r] = s;
                rmax[r] = fmaxf(rmax[r], s);
            }
        }
        #pragma unroll
        for (int r = 0; r < 4; ++r) {
            #pragma unroll
            for (int d = 1; d < 16; d <<= 1)
                rmax[r] = fmaxf(rmax[r], __shfl_xor(rmax[r], d));
        }
        float alf[4];
        #pragma unroll
        for (int r = 0; r < 4; ++r) {
            const float mn = fmaxf(m_r[r], rmax[r]);
            alf[r] = __expf(m_r[r] - mn);
            m_r[r] = mn;
        }

        // ---- exp, band (raw logits), sums, P -> LDS ----
        float rs[4] = {0,0,0,0}, rts[4] = {0,0,0,0};
        #pragma unroll
        for (int jt = 0; jt < 4; ++jt) {
            const int kl = jt*16 + l16;
            #pragma unroll
            for (int r = 0; r < 4; ++r) {
                const float s = accS[jt][r];
                const float p = __expf(s - m_r[r]);
                rs[r] += p;
                if (mode == 2) rts[r] += p;
                else if (mode == 1) {
                    int dk = (k0 + kl) - (q0 + qrow + r);
                    if (dk > MAX_REL) rts[r] += p;
                    else if (dk >= -MAX_REL) band[(qrow + r)*33 + dk + MAX_REL] = s;
                }
                Ps[(qrow + r)*SP + kl] = (_Float16)p;
            }
        }
        #pragma unroll
        for (int r = 0; r < 4; ++r) {
            #pragma unroll
            for (int d = 1; d < 16; d <<= 1) rs[r] += __shfl_xor(rs[r], d);
        }
        if (mode != 0) {
            #pragma unroll
            for (int r = 0; r < 4; ++r) {
                #pragma unroll
                for (int d = 1; d < 16; d <<= 1) rts[r] += __shfl_xor(rts[r], d);
            }
        }
        #pragma unroll
        for (int r = 0; r < 4; ++r) {
            l_r[r]  = l_r[r]  * alf[r] + rs[r];
            rt_r[r] = rt_r[r] * alf[r] + rts[r];
        }
        #pragma unroll
        for (int dt = 0; dt < 4; ++dt)
            #pragma unroll
            for (int r = 0; r < 4; ++r) accO[dt][r] *= alf[r];

        // ---- O += P V ----
        #pragma unroll
        for (int ks2 = 0; ks2 < 2; ++ks2) {
            const int ko = ks2*32 + quad*8;
            const int k8n = ks2*4 + quad;
            f16x8 pf = *(const f16x8*)&Ps[(w*16 + l16)*SP + ko];
            #pragma unroll
            for (int dt = 0; dt < 4; ++dt) {
                const int d = dt*16 + l16;
                const int xd = (d >> 3) & 7;
                f16x8 vf = *(const f16x8*)&Vt[buf][d*SP + ((k8n ^ xd) << 3)];
                accO[dt] = __builtin_amdgcn_mfma_f32_16x16x32_f16(pf, vf, accO[dt], 0, 0, 0);
            }
        }

        // ---- write prefetched tile t+1 into other buffer ----
        if (t + 1 < SEQ/KT) {
            const int nb = buf ^ 1;
            #pragma unroll
            for (int g = 0; g < 2; ++g) {
                f16x8 hh;
                #pragma unroll
                for (int j = 0; j < 8; ++j) hh[j] = (_Float16)ka[g*8+j];
                *(f16x8*)&Ks[nb][sr*SP + sc + g*8] = hh;
            }
            #pragma unroll
            for (int i = 0; i < 8; ++i) {
                const int d = vd + i;
                const int xd = (d >> 3) & 7;
                f16x2 pr; pr[0] = (_Float16)va8[i]; pr[1] = (_Float16)vb8[i];
                *(f16x2*)&Vt[nb][d*SP + ((k8 ^ xd) << 3) + klo] = pr;
            }
        }
        __syncthreads();
    }

    // ---- epilogue: band logits -> probs (+ tails) -> Ps fp16, w2 via MFMA ----
    float bsp[4] = {0,0,0,0};
    float ej0[4], ej1[4], e32[4];
    #pragma unroll
    for (int r = 0; r < 4; ++r) {
        const int ql = qrow + r;
        ej0[r] = __expf(band[ql*33 + l16]      - m_r[r]);
        ej1[r] = __expf(band[ql*33 + 16 + l16] - m_r[r]);
        bsp[r] = ej0[r] + ej1[r];
        if (l16 == 0) { e32[r] = __expf(band[ql*33 + 32] - m_r[r]); bsp[r] += e32[r]; }
    }
    #pragma unroll
    for (int r = 0; r < 4; ++r) {
        #pragma unroll
        for (int d = 1; d < 16; d <<= 1) bsp[r] += __shfl_xor(bsp[r], d);
    }
    #pragma unroll
    for (int r = 0; r < 4; ++r) {
        const int ql = qrow + r;
        const float Pl = l_r[r] - rt_r[r] - bsp[r];
        Ps[ql*SP + l16]      = (_Float16)((l16 == 0) ? (ej0[r] + Pl) : ej0[r]);
        Ps[ql*SP + 16 + l16] = (_Float16)ej1[r];
        Ps[ql*SP + 32 + l16] = (_Float16)((l16 == 0) ? (e32[r] + rt_r[r]) : 0.f);
        Ps[ql*SP + 48 + l16] = (_Float16)0.f;
    }

    f32x4 accW[4];
    #pragma unroll
    for (int dt = 0; dt < 4; ++dt) accW[dt] = (f32x4){0.f,0.f,0.f,0.f};
    #pragma unroll
    for (int ks2 = 0; ks2 < 2; ++ks2) {
        const int ko = ks2*32 + quad*8;
        f16x8 pf = *(const f16x8*)&Ps[(w*16 + l16)*SP + ko];
        #pragma unroll
        for (int dt = 0; dt < 4; ++dt) {
            f16x8 ef = *(const f16x8*)&EvT[(dt*16 + l16)*SP + ko];
            accW[dt] = __builtin_amdgcn_mfma_f32_16x16x32_f16(pf, ef, accW[dt], 0, 0, 0);
        }
    }
    #pragma unroll
    for (int r = 0; r < 4; ++r) {
        const float linv = 1.f / l_r[r];
        const int qg = q0 + qrow + r;
        #pragma unroll
        for (int dt = 0; dt < 4; ++dt) {
            x[((size_t)(b*SEQ + qg))*D_MODEL + h*HEAD_DIM + dt*16 + l16] =
                (accO[dt][r] + accW[dt][r]) * linv;
        }
    }
}

extern "C" void kernel_launch(void* const* d_in, const int* in_sizes, int n_in,
                              void* d_out, int out_size, void* d_ws, size_t ws_size,
                              hipStream_t stream) {
    const float* query = (const float*)d_in[0];
    const float* key   = (const float*)d_in[1];
    const float* value = (const float*)d_in[2];
    const int*   mask  = (const int*)d_in[3];
    const float* Wq = (const float*)d_in[4];
    const float* bq = (const float*)d_in[5];
    const float* Wk = (const float*)d_in[6];
    const float* bk = (const float*)d_in[7];
    const float* Wv = (const float*)d_in[8];
    const float* bv = (const float*)d_in[9];
    const float* Wo = (const float*)d_in[10];
    const float* bo = (const float*)d_in[11];
    const float* emb_k = (const float*)d_in[12];
    const float* emb_v = (const float*)d_in[13];
    float* out = (float*)d_out;
    float* ws  = (float*)d_ws;

    const int M = BATCH * SEQ;  // 4096
    float* qb = ws;
    float* kb = qb + (size_t)M * D_MODEL;
    float* vb = kb + (size_t)M * D_MODEL;
    float* xb = vb + (size_t)M * D_MODEL;

    // fused QKV projections (z = 3)
    dim3 gQKV(D_MODEL / GBN, M / GBM, 3), tB(256);
    gemm_bt_bias_f16v2<<<gQKV, tB, 0, stream>>>(
        query, key, value, Wq, Wk, Wv, bq, bk, bv, qb, kb, vb, M, D_MODEL, D_MODEL);

    dim3 gA(SEQ/QT, N_HEADS, BATCH);
    attn_flash_mfma2<<<gA, dim3(256), 0, stream>>>(qb, kb, vb, mask, emb_k, emb_v, xb);

    dim3 gO(D_MODEL / GBN, M / GBM, 1);
    gemm_bt_bias_f16v2<<<gO, tB, 0, stream>>>(
        xb, xb, xb, Wo, Wo, Wo, bo, bo, bo, out, out, out, M, D_MODEL, D_MODEL);
}

// Round 7
// 400.914 us; speedup vs baseline: 13.1830x; 1.0707x over previous
//
#include <hip/hip_runtime.h>
#include <math.h>

#define D_MODEL 1024
#define N_HEADS 16
#define HEAD_DIM 64
#define MAX_REL 16
#define SEQ 1024
#define BATCH 4

typedef _Float16 f16x8 __attribute__((ext_vector_type(8)));
typedef _Float16 f16x2 __attribute__((ext_vector_type(2)));
typedef float f32x4 __attribute__((ext_vector_type(4)));
typedef unsigned long long u64;

// ---------------- mask -> bitmask pre-pass ----------------
__global__ __launch_bounds__(256) void mask_compress(
    const int* __restrict__ mask, u64* __restrict__ mbits, int n64)
{
    const int wid  = (blockIdx.x * 256 + threadIdx.x) >> 6;
    const int lane = threadIdx.x & 63;
    if (wid < n64) {
        const int vv = mask[(size_t)wid * 64 + lane];
        const u64 bal = __ballot(vv != 0);
        if (lane == 0) mbits[wid] = bal;
    }
}

// ---------------- QKV GEMM: C(fp16) = A(fp32) * W^T + bias, single fp16 pass
#define GBM 64
#define GBN 128
#define GBK 64
#define LDA 72

__global__ __launch_bounds__(256) void gemm_qkv_f16(
    const float* A0, const float* A1, const float* A2,
    const float* W0, const float* W1, const float* W2,
    const float* b0, const float* b1, const float* b2,
    _Float16* C0, _Float16* C1, _Float16* C2, int M, int N, int K)
{
    __shared__ _Float16 Ah[GBM * LDA];
    __shared__ _Float16 Wh[GBN * LDA];

    const int z = blockIdx.z;
    const float* A = (z == 0) ? A0 : (z == 1) ? A1 : A2;
    const float* W = (z == 0) ? W0 : (z == 1) ? W1 : W2;
    const float* bias = (z == 0) ? b0 : (z == 1) ? b1 : b2;
    _Float16* C = (z == 0) ? C0 : (z == 1) ? C1 : C2;

    const int tid  = threadIdx.x;
    const int m0   = blockIdx.y * GBM;
    const int n0   = blockIdx.x * GBN;
    const int lane = tid & 63;
    const int w    = tid >> 6;
    const int quad = lane >> 4;
    const int l16  = lane & 15;
    const int wm   = (w & 1) * 32;
    const int wn   = (w >> 1) * 64;

    const int sra = tid >> 2, sca = (tid & 3) * 16;   // A: 64 rows x 16 cols
    const int srw = tid >> 1, scw = (tid & 1) * 32;   // W: 128 rows x 32 cols

    const float* Ab = A + (size_t)(m0 + sra) * K + sca;
    const float* Wb = W + (size_t)(n0 + srw) * K + scw;

    f32x4 acc[2][4];
    #pragma unroll
    for (int i = 0; i < 2; ++i)
        #pragma unroll
        for (int j = 0; j < 4; ++j)
            acc[i][j] = (f32x4){0.f, 0.f, 0.f, 0.f};

    for (int k0 = 0; k0 < K; k0 += GBK) {
        __syncthreads();
        #pragma unroll
        for (int c = 0; c < 16; c += 8) {
            float4 x0 = *(const float4*)(Ab + k0 + c);
            float4 x1 = *(const float4*)(Ab + k0 + c + 4);
            float xs[8] = {x0.x, x0.y, x0.z, x0.w, x1.x, x1.y, x1.z, x1.w};
            f16x8 hi;
            #pragma unroll
            for (int j = 0; j < 8; ++j) hi[j] = (_Float16)xs[j];
            *(f16x8*)&Ah[sra * LDA + sca + c] = hi;
        }
        #pragma unroll
        for (int c = 0; c < 32; c += 8) {
            float4 y0 = *(const float4*)(Wb + k0 + c);
            float4 y1 = *(const float4*)(Wb + k0 + c + 4);
            float ys[8] = {y0.x, y0.y, y0.z, y0.w, y1.x, y1.y, y1.z, y1.w};
            f16x8 wh;
            #pragma unroll
            for (int j = 0; j < 8; ++j) wh[j] = (_Float16)ys[j];
            *(f16x8*)&Wh[srw * LDA + scw + c] = wh;
        }
        __syncthreads();

        #pragma unroll
        for (int ks = 0; ks < GBK; ks += 32) {
            const int kb = ks + quad * 8;
            f16x8 af[2], bf[4];
            #pragma unroll
            for (int i = 0; i < 2; ++i)
                af[i] = *(const f16x8*)&Ah[(wm + i*16 + l16) * LDA + kb];
            #pragma unroll
            for (int j = 0; j < 4; ++j)
                bf[j] = *(const f16x8*)&Wh[(wn + j*16 + l16) * LDA + kb];
            #pragma unroll
            for (int i = 0; i < 2; ++i)
                #pragma unroll
                for (int j = 0; j < 4; ++j)
                    acc[i][j] = __builtin_amdgcn_mfma_f32_16x16x32_f16(af[i], bf[j], acc[i][j], 0, 0, 0);
        }
    }

    const int cbase = n0 + wn + l16;
    const int rbase = m0 + wm + quad * 4;
    #pragma unroll
    for (int j = 0; j < 4; ++j) {
        const int col = cbase + j * 16;
        const float bv = bias[col];
        #pragma unroll
        for (int i = 0; i < 2; ++i) {
            #pragma unroll
            for (int r = 0; r < 4; ++r) {
                const int m = rbase + i * 16 + r;
                C[(size_t)m * N + col] = (_Float16)(acc[i][j][r] + bv);
            }
        }
    }
}

// ---------------- Out GEMM: C(fp32) = A(fp16) * W^T + bias ----------------
__global__ __launch_bounds__(256) void gemm_out_f32(
    const _Float16* __restrict__ A, const float* __restrict__ W,
    const float* __restrict__ bias, float* __restrict__ C, int M, int N, int K)
{
    __shared__ _Float16 Ah[GBM * LDA];
    __shared__ _Float16 Wh[GBN * LDA];

    const int tid  = threadIdx.x;
    const int m0   = blockIdx.y * GBM;
    const int n0   = blockIdx.x * GBN;
    const int lane = tid & 63;
    const int w    = tid >> 6;
    const int quad = lane >> 4;
    const int l16  = lane & 15;
    const int wm   = (w & 1) * 32;
    const int wn   = (w >> 1) * 64;

    const int sra = tid >> 2, sca = (tid & 3) * 16;
    const int srw = tid >> 1, scw = (tid & 1) * 32;

    const _Float16* Ab = A + (size_t)(m0 + sra) * K + sca;
    const float* Wb = W + (size_t)(n0 + srw) * K + scw;

    f32x4 acc[2][4];
    #pragma unroll
    for (int i = 0; i < 2; ++i)
        #pragma unroll
        for (int j = 0; j < 4; ++j)
            acc[i][j] = (f32x4){0.f, 0.f, 0.f, 0.f};

    for (int k0 = 0; k0 < K; k0 += GBK) {
        __syncthreads();
        #pragma unroll
        for (int c = 0; c < 16; c += 8)
            *(f16x8*)&Ah[sra * LDA + sca + c] = *(const f16x8*)(Ab + k0 + c);
        #pragma unroll
        for (int c = 0; c < 32; c += 8) {
            float4 y0 = *(const float4*)(Wb + k0 + c);
            float4 y1 = *(const float4*)(Wb + k0 + c + 4);
            float ys[8] = {y0.x, y0.y, y0.z, y0.w, y1.x, y1.y, y1.z, y1.w};
            f16x8 wh;
            #pragma unroll
            for (int j = 0; j < 8; ++j) wh[j] = (_Float16)ys[j];
            *(f16x8*)&Wh[srw * LDA + scw + c] = wh;
        }
        __syncthreads();

        #pragma unroll
        for (int ks = 0; ks < GBK; ks += 32) {
            const int kb = ks + quad * 8;
            f16x8 af[2], bf[4];
            #pragma unroll
            for (int i = 0; i < 2; ++i)
                af[i] = *(const f16x8*)&Ah[(wm + i*16 + l16) * LDA + kb];
            #pragma unroll
            for (int j = 0; j < 4; ++j)
                bf[j] = *(const f16x8*)&Wh[(wn + j*16 + l16) * LDA + kb];
            #pragma unroll
            for (int i = 0; i < 2; ++i)
                #pragma unroll
                for (int j = 0; j < 4; ++j)
                    acc[i][j] = __builtin_amdgcn_mfma_f32_16x16x32_f16(af[i], bf[j], acc[i][j], 0, 0, 0);
        }
    }

    const int cbase = n0 + wn + l16;
    const int rbase = m0 + wm + quad * 4;
    #pragma unroll
    for (int j = 0; j < 4; ++j) {
        const int col = cbase + j * 16;
        const float bv = bias[col];
        #pragma unroll
        for (int i = 0; i < 2; ++i) {
            #pragma unroll
            for (int r = 0; r < 4; ++r) {
                const int m = rbase + i * 16 + r;
                C[(size_t)m * N + col] = acc[i][j][r] + bv;
            }
        }
    }
}

// ---------------- Flash attention, all-fp16 inputs, bitmask, MFMA ----------
#define QT 64
#define KT 64
#define SP 72
#define EVP 40

__global__ __launch_bounds__(256) void attn_flash_mfma3(
    const _Float16* __restrict__ q, const _Float16* __restrict__ kg,
    const _Float16* __restrict__ v, const u64* __restrict__ mbits,
    const float* __restrict__ emb_k, const float* __restrict__ emb_v,
    _Float16* __restrict__ x)
{
    __shared__ _Float16 Ks[2][KT * SP];
    __shared__ _Float16 Vt[2][HEAD_DIM * SP];
    __shared__ _Float16 Ps[QT * SP];
    __shared__ _Float16 EvT[HEAD_DIM * EVP];  // emb_v^T [d][j], j<32
    __shared__ _Float16 pbh[QT * 33];
    __shared__ _Float16 bandh[QT * 33];       // raw logits (fp16)

    const int qt = blockIdx.x, h = blockIdx.y, b = blockIdx.z;
    const int q0 = qt * QT;
    const int tid = threadIdx.x;
    const int lane = tid & 63;
    const int w = tid >> 6;
    const int quad = lane >> 4;
    const int l16 = lane & 15;
    const int qrow = w * 16 + quad * 4;

    const int sr = tid >> 2, sc = (tid & 3) * 16;        // K staging
    const int vk = (tid & 31) * 2, vd = (tid >> 5) * 8;  // V staging
    const int k8 = vk >> 3, klo = vk & 7;

    // ---- Q fragments -> registers ----
    f16x8 qf[2];
    {
        const _Float16* qp = q + ((size_t)(b*SEQ + q0 + w*16 + l16))*D_MODEL + h*HEAD_DIM;
        qf[0] = *(const f16x8*)(qp + quad*8);
        qf[1] = *(const f16x8*)(qp + 32 + quad*8);
    }

    // ---- stage emb_k into Ks[0] (48 rows, zero-pad); emb_v^T into EvT ----
    if (sr < 48) {
        #pragma unroll
        for (int c = 0; c < 16; ++c) {
            float val = (sr < 33) ? emb_k[sr*HEAD_DIM + sc + c] : 0.f;
            Ks[0][sr*SP + sc + c] = (_Float16)val;
        }
    }
    for (int idx = tid; idx < HEAD_DIM*EVP; idx += 256) {
        const int d = idx / EVP, j = idx % EVP;
        float val = (j < 32) ? emb_v[j*HEAD_DIM + d] : 0.f;
        EvT[d*EVP + j] = (_Float16)val;
    }
    for (int i = tid; i < QT*33; i += 256) bandh[i] = (_Float16)(-60000.f);
    __syncthreads();

    // ---- pb = Q @ emb_k^T via MFMA (single pass) ----
    f32x4 accP[3];
    #pragma unroll
    for (int jt = 0; jt < 3; ++jt) accP[jt] = (f32x4){0.f,0.f,0.f,0.f};
    #pragma unroll
    for (int ks2 = 0; ks2 < 2; ++ks2) {
        const int ko = ks2*32 + quad*8;
        #pragma unroll
        for (int jt = 0; jt < 3; ++jt) {
            f16x8 bf = *(const f16x8*)&Ks[0][(jt*16 + l16)*SP + ko];
            accP[jt] = __builtin_amdgcn_mfma_f32_16x16x32_f16(qf[ks2], bf, accP[jt], 0, 0, 0);
        }
    }
    #pragma unroll
    for (int jt = 0; jt < 3; ++jt) {
        const int j = jt*16 + l16;
        if (j < 33) {
            #pragma unroll
            for (int r = 0; r < 4; ++r) pbh[(qrow + r)*33 + j] = (_Float16)accP[jt][r];
        }
    }
    float pb0r[4], pb32r[4];
    #pragma unroll
    for (int r = 0; r < 4; ++r) {
        pb0r[r]  = __shfl(accP[0][r], quad * 16);
        pb32r[r] = __shfl(accP[2][r], quad * 16);
    }
    __syncthreads();   // pbh visible; emb_k reads done before Ks[0] reuse

    float m_r[4], l_r[4], rt_r[4];
    #pragma unroll
    for (int r = 0; r < 4; ++r) { m_r[r] = -1e30f; l_r[r] = 0.f; rt_r[r] = 0.f; }
    f32x4 accO[4];
    #pragma unroll
    for (int dt = 0; dt < 4; ++dt) accO[dt] = (f32x4){0.f,0.f,0.f,0.f};

    f16x8 kp0, kp1, vp0, vp1;  // prefetch regs

    // ---- prologue: stage tile 0 ----
    {
        const _Float16* kp = kg + ((size_t)(b*SEQ + sr))*D_MODEL + h*HEAD_DIM + sc;
        kp0 = *(const f16x8*)(kp);
        kp1 = *(const f16x8*)(kp + 8);
        const _Float16* vp = v + ((size_t)(b*SEQ + vk))*D_MODEL + h*HEAD_DIM + vd;
        vp0 = *(const f16x8*)(vp);
        vp1 = *(const f16x8*)(vp + D_MODEL);
        *(f16x8*)&Ks[0][sr*SP + sc]     = kp0;
        *(f16x8*)&Ks[0][sr*SP + sc + 8] = kp1;
        #pragma unroll
        for (int i = 0; i < 8; ++i) {
            const int d = vd + i;
            const int xd = (d >> 3) & 7;
            f16x2 pr; pr[0] = vp0[i]; pr[1] = vp1[i];
            *(f16x2*)&Vt[0][d*SP + ((k8 ^ xd) << 3) + klo] = pr;
        }
    }
    __syncthreads();

    const float inv_scale = 0.125f;

    for (int t = 0; t < SEQ/KT; ++t) {
        const int buf = t & 1;
        const int k0 = t * KT;

        // ---- prefetch tile t+1 (global -> regs) ----
        if (t + 1 < SEQ/KT) {
            const int kn = k0 + KT;
            const _Float16* kp = kg + ((size_t)(b*SEQ + kn + sr))*D_MODEL + h*HEAD_DIM + sc;
            kp0 = *(const f16x8*)(kp);
            kp1 = *(const f16x8*)(kp + 8);
            const _Float16* vp = v + ((size_t)(b*SEQ + kn + vk))*D_MODEL + h*HEAD_DIM + vd;
            vp0 = *(const f16x8*)(vp);
            vp1 = *(const f16x8*)(vp + D_MODEL);
        }

        // ---- mask bits for this tile ----
        u64 mw[4];
        {
            const u64* mb = mbits + ((size_t)(b*SEQ + q0 + qrow)) * (SEQ/64) + t;
            #pragma unroll
            for (int r = 0; r < 4; ++r) mw[r] = mb[(size_t)r * (SEQ/64)];
        }

        // ---- S = Q K^T ----
        f32x4 accS[4];
        #pragma unroll
        for (int jt = 0; jt < 4; ++jt) accS[jt] = (f32x4){0.f,0.f,0.f,0.f};
        #pragma unroll
        for (int ks2 = 0; ks2 < 2; ++ks2) {
            const int ko = ks2*32 + quad*8;
            #pragma unroll
            for (int jt = 0; jt < 4; ++jt) {
                f16x8 bf = *(const f16x8*)&Ks[buf][(jt*16 + l16)*SP + ko];
                accS[jt] = __builtin_amdgcn_mfma_f32_16x16x32_f16(qf[ks2], bf, accS[jt], 0, 0, 0);
            }
        }

        const int kq = k0 - q0;
        const int mode = (kq <= -128) ? 0 : (kq >= 128 ? 2 : 1);

        // ---- bias + scale + mask; row-max ----
        float rmax[4] = {-1e30f,-1e30f,-1e30f,-1e30f};
        #pragma unroll
        for (int jt = 0; jt < 4; ++jt) {
            const int kl = jt*16 + l16;
            #pragma unroll
            for (int r = 0; r < 4; ++r) {
                float pv;
                if (mode == 0) pv = pb0r[r];
                else if (mode == 2) pv = pb32r[r];
                else {
                    int dk = (k0 + kl) - (q0 + qrow + r);
                    int ii = (dk < -MAX_REL ? -MAX_REL : (dk > MAX_REL ? MAX_REL : dk)) + MAX_REL;
                    pv = (float)pbh[(qrow + r)*33 + ii];
                }
                float s = (accS[jt][r] + pv) * inv_scale;
                if (!((mw[r] >> kl) & 1ull)) s = -1e30f;
                accS[jt][r] = s;
                rmax[r] = fmaxf(rmax[r], s);
            }
        }
        #pragma unroll
        for (int r = 0; r < 4; ++r) {
            #pragma unroll
            for (int d = 1; d < 16; d <<= 1)
                rmax[r] = fmaxf(rmax[r], __shfl_xor(rmax[r], d));
        }
        float alf[4];
        #pragma unroll
        for (int r = 0; r < 4; ++r) {
            const float mn = fmaxf(m_r[r], rmax[r]);
            alf[r] = __expf(m_r[r] - mn);
            m_r[r] = mn;
        }

        // ---- exp, band (raw logits), sums, P -> LDS ----
        float rs[4] = {0,0,0,0}, rts[4] = {0,0,0,0};
        #pragma unroll
        for (int jt = 0; jt < 4; ++jt) {
            const int kl = jt*16 + l16;
            #pragma unroll
            for (int r = 0; r < 4; ++r) {
                const float s = accS[jt][r];
                const float p = __expf(s - m_r[r]);
                rs[r] += p;
                if (mode == 2) rts[r] += p;
                else if (mode == 1) {
                    int dk = (k0 + kl) - (q0 + qrow + r);
                    if (dk > MAX_REL) rts[r] += p;
                    else if (dk >= -MAX_REL) bandh[(qrow + r)*33 + dk + MAX_REL] = (_Float16)s;
                }
                Ps[(qrow + r)*SP + kl] = (_Float16)p;
            }
        }
        #pragma unroll
        for (int r = 0; r < 4; ++r) {
            #pragma unroll
            for (int d = 1; d < 16; d <<= 1) rs[r] += __shfl_xor(rs[r], d);
        }
        if (mode != 0) {
            #pragma unroll
            for (int r = 0; r < 4; ++r) {
                #pragma unroll
                for (int d = 1; d < 16; d <<= 1) rts[r] += __shfl_xor(rts[r], d);
            }
        }
        #pragma unroll
        for (int r = 0; r < 4; ++r) {
            l_r[r]  = l_r[r]  * alf[r] + rs[r];
            rt_r[r] = rt_r[r] * alf[r] + rts[r];
        }
        #pragma unroll
        for (int dt = 0; dt < 4; ++dt)
            #pragma unroll
            for (int r = 0; r < 4; ++r) accO[dt][r] *= alf[r];

        // ---- O += P V ----
        #pragma unroll
        for (int ks2 = 0; ks2 < 2; ++ks2) {
            const int ko = ks2*32 + quad*8;
            const int k8n = ks2*4 + quad;
            f16x8 pf = *(const f16x8*)&Ps[(w*16 + l16)*SP + ko];
            #pragma unroll
            for (int dt = 0; dt < 4; ++dt) {
                const int d = dt*16 + l16;
                const int xd = (d >> 3) & 7;
                f16x8 vf = *(const f16x8*)&Vt[buf][d*SP + ((k8n ^ xd) << 3)];
                accO[dt] = __builtin_amdgcn_mfma_f32_16x16x32_f16(pf, vf, accO[dt], 0, 0, 0);
            }
        }

        // ---- write prefetched tile into other buffer ----
        if (t + 1 < SEQ/KT) {
            const int nb = buf ^ 1;
            *(f16x8*)&Ks[nb][sr*SP + sc]     = kp0;
            *(f16x8*)&Ks[nb][sr*SP + sc + 8] = kp1;
            #pragma unroll
            for (int i = 0; i < 8; ++i) {
                const int d = vd + i;
                const int xd = (d >> 3) & 7;
                f16x2 pr; pr[0] = vp0[i]; pr[1] = vp1[i];
                *(f16x2*)&Vt[nb][d*SP + ((k8 ^ xd) << 3) + klo] = pr;
            }
        }
        __syncthreads();
    }

    // ---- epilogue: band logits -> probs, w2 via MFMA over cols 0..31 ----
    float ej0[4], ej1[4], e32[4], bsp[4];
    #pragma unroll
    for (int r = 0; r < 4; ++r) {
        const int ql = qrow + r;
        ej0[r] = __expf((float)bandh[ql*33 + l16]      - m_r[r]);
        ej1[r] = __expf((float)bandh[ql*33 + 16 + l16] - m_r[r]);
        e32[r] = __expf((float)bandh[ql*33 + 32]       - m_r[r]);
        bsp[r] = ej0[r] + ej1[r];
    }
    #pragma unroll
    for (int r = 0; r < 4; ++r) {
        #pragma unroll
        for (int d = 1; d < 16; d <<= 1) bsp[r] += __shfl_xor(bsp[r], d);
    }
    #pragma unroll
    for (int r = 0; r < 4; ++r) {
        const int ql = qrow + r;
        const float Pl = l_r[r] - rt_r[r] - (bsp[r] + e32[r]);
        Ps[ql*SP + l16]      = (_Float16)((l16 == 0) ? (ej0[r] + Pl) : ej0[r]);
        Ps[ql*SP + 16 + l16] = (_Float16)ej1[r];
    }

    f32x4 accW[4];
    #pragma unroll
    for (int dt = 0; dt < 4; ++dt) accW[dt] = (f32x4){0.f,0.f,0.f,0.f};
    {
        f16x8 pf = *(const f16x8*)&Ps[(w*16 + l16)*SP + quad*8];
        #pragma unroll
        for (int dt = 0; dt < 4; ++dt) {
            f16x8 ef = *(const f16x8*)&EvT[(dt*16 + l16)*EVP + quad*8];
            accW[dt] = __builtin_amdgcn_mfma_f32_16x16x32_f16(pf, ef, accW[dt], 0, 0, 0);
        }
    }
    #pragma unroll
    for (int r = 0; r < 4; ++r) {
        const float p32 = e32[r] + rt_r[r];
        const float linv = 1.f / l_r[r];
        const int qg = q0 + qrow + r;
        #pragma unroll
        for (int dt = 0; dt < 4; ++dt) {
            const float w32 = emb_v[32*HEAD_DIM + dt*16 + l16];
            x[((size_t)(b*SEQ + qg))*D_MODEL + h*HEAD_DIM + dt*16 + l16] =
                (_Float16)((accO[dt][r] + accW[dt][r] + p32 * w32) * linv);
        }
    }
}

extern "C" void kernel_launch(void* const* d_in, const int* in_sizes, int n_in,
                              void* d_out, int out_size, void* d_ws, size_t ws_size,
                              hipStream_t stream) {
    const float* query = (const float*)d_in[0];
    const float* key   = (const float*)d_in[1];
    const float* value = (const float*)d_in[2];
    const int*   mask  = (const int*)d_in[3];
    const float* Wq = (const float*)d_in[4];
    const float* bq = (const float*)d_in[5];
    const float* Wk = (const float*)d_in[6];
    const float* bk = (const float*)d_in[7];
    const float* Wv = (const float*)d_in[8];
    const float* bv = (const float*)d_in[9];
    const float* Wo = (const float*)d_in[10];
    const float* bo = (const float*)d_in[11];
    const float* emb_k = (const float*)d_in[12];
    const float* emb_v = (const float*)d_in[13];
    float* out = (float*)d_out;

    const int M = BATCH * SEQ;  // 4096
    _Float16* qh = (_Float16*)d_ws;
    _Float16* kh = qh + (size_t)M * D_MODEL;
    _Float16* vh = kh + (size_t)M * D_MODEL;
    _Float16* xh = vh + (size_t)M * D_MODEL;
    u64* mbits = (u64*)(xh + (size_t)M * D_MODEL);
    const int n64 = BATCH * SEQ * (SEQ / 64);

    mask_compress<<<dim3((n64*64)/256), dim3(256), 0, stream>>>(mask, mbits, n64);

    dim3 gQKV(D_MODEL / GBN, M / GBM, 3), tB(256);
    gemm_qkv_f16<<<gQKV, tB, 0, stream>>>(
        query, key, value, Wq, Wk, Wv, bq, bk, bv, qh, kh, vh, M, D_MODEL, D_MODEL);

    dim3 gA(SEQ/QT, N_HEADS, BATCH);
    attn_flash_mfma3<<<gA, dim3(256), 0, stream>>>(qh, kh, vh, mbits, emb_k, emb_v, xh);

    dim3 gO(D_MODEL / GBN, M / GBM);
    gemm_out_f32<<<gO, tB, 0, stream>>>(xh, Wo, bo, out, M, D_MODEL, D_MODEL);
}

// Round 8
// 316.692 us; speedup vs baseline: 16.6889x; 1.2659x over previous
//
#include <hip/hip_runtime.h>
#include <math.h>

#define D_MODEL 1024
#define N_HEADS 16
#define HEAD_DIM 64
#define MAX_REL 16
#define SEQ 1024
#define BATCH 4

typedef _Float16 f16x8 __attribute__((ext_vector_type(8)));
typedef _Float16 f16x4 __attribute__((ext_vector_type(4)));
typedef _Float16 f16x2 __attribute__((ext_vector_type(2)));
typedef float f32x4 __attribute__((ext_vector_type(4)));
typedef unsigned long long u64;

// async global->LDS 16B copy (CK-style address-space casts)
__device__ __forceinline__ void gld_lds16(const _Float16* g, _Float16* l) {
    __builtin_amdgcn_global_load_lds(
        (const __attribute__((address_space(1))) void*)(uintptr_t)g,
        (__attribute__((address_space(3))) void*)(uintptr_t)l, 16, 0, 0);
}

// ---------------- mask -> bitmask pre-pass ----------------
__global__ __launch_bounds__(256) void mask_compress(
    const int* __restrict__ mask, u64* __restrict__ mbits, int n64)
{
    const int wid  = (blockIdx.x * 256 + threadIdx.x) >> 6;
    const int lane = threadIdx.x & 63;
    if (wid < n64) {
        const int vv = mask[(size_t)wid * 64 + lane];
        const u64 bal = __ballot(vv != 0);
        if (lane == 0) mbits[wid] = bal;
    }
}

// ---------------- fp32 -> fp16 conversion pre-pass ----------------
// 16M floats: q(4M) k(4M) v(4M) Wq Wk Wv Wo (1M each). 4 floats/thread.
__global__ __launch_bounds__(256) void cvt_all(
    const float* __restrict__ q, const float* __restrict__ k, const float* __restrict__ v,
    const float* __restrict__ Wq, const float* __restrict__ Wk,
    const float* __restrict__ Wv, const float* __restrict__ Wo,
    _Float16* __restrict__ qin, _Float16* __restrict__ kin, _Float16* __restrict__ vin,
    _Float16* __restrict__ wq, _Float16* __restrict__ wk,
    _Float16* __restrict__ wv, _Float16* __restrict__ wo)
{
    const size_t M1 = 1u << 20;
    size_t f = ((size_t)blockIdx.x * 256 + threadIdx.x) * 4;
    const float* src; _Float16* dst; size_t off;
    if (f < 4*M1)       { src = q; dst = qin; off = f; }
    else if (f < 8*M1)  { src = k; dst = kin; off = f - 4*M1; }
    else if (f < 12*M1) { src = v; dst = vin; off = f - 8*M1; }
    else {
        int u = (int)(f >> 20) - 12;
        src = (u==0)?Wq:(u==1)?Wk:(u==2)?Wv:Wo;
        dst = (u==0)?wq:(u==1)?wk:(u==2)?wv:wo;
        off = f & (M1 - 1);
    }
    float4 x = *(const float4*)(src + off);
    f16x4 h; h[0]=(_Float16)x.x; h[1]=(_Float16)x.y; h[2]=(_Float16)x.z; h[3]=(_Float16)x.w;
    *(f16x4*)(dst + off) = h;
}

// ---------------- GEMM: C = A * W^T + bias, fp16 in, async LDS staging -----
// 128x128x64 tile, 4 waves (2x2), global_load_lds(16B) with XOR-swizzled
// layout: element (m,k) at As[m*64 + ((k>>3)^(m&7))*8 + (k&7)].
// Staging entry e (0..1023): m=e>>3, k8=(e&7)^(m&7) -> wave-contiguous LDS,
// row-contiguous global, 2-way-max LDS banks on ds_read_b128.
#define TBM 128
#define TBN 128
#define TBK 64

template <typename CT>
__global__ __launch_bounds__(256) void gemm_f16async(
    const _Float16* A0, const _Float16* A1, const _Float16* A2,
    const _Float16* W0, const _Float16* W1, const _Float16* W2,
    const float* b0, const float* b1, const float* b2,
    CT* C0, CT* C1, CT* C2, int M, int N, int K)
{
    __shared__ _Float16 As[TBM * TBK];
    __shared__ _Float16 Ws[TBN * TBK];

    const int z = blockIdx.z;
    const _Float16* A = (z==0)?A0:(z==1)?A1:A2;
    const _Float16* W = (z==0)?W0:(z==1)?W1:W2;
    const float* bias = (z==0)?b0:(z==1)?b1:b2;
    CT* C = (z==0)?C0:(z==1)?C1:C2;

    const int tid = threadIdx.x;
    const int lane = tid & 63;
    const int w = tid >> 6;
    const int quad = lane >> 4;
    const int l16 = lane & 15;
    const int m0 = blockIdx.y * TBM;
    const int n0 = blockIdx.x * TBN;
    const int wm = (w & 1) * 64;
    const int wn = (w >> 1) * 64;

    int em[4], ek[4];
    #pragma unroll
    for (int i = 0; i < 4; ++i) {
        const int e = i * 256 + tid;
        em[i] = e >> 3;
        ek[i] = (e & 7) ^ (em[i] & 7);
    }

    f32x4 acc[4][4];
    #pragma unroll
    for (int i = 0; i < 4; ++i)
        #pragma unroll
        for (int j = 0; j < 4; ++j)
            acc[i][j] = (f32x4){0.f, 0.f, 0.f, 0.f};

    for (int kt = 0; kt < K; kt += TBK) {
        if (kt) __syncthreads();
        #pragma unroll
        for (int i = 0; i < 4; ++i) {
            const int e = i * 256 + tid;
            gld_lds16(A + (size_t)(m0 + em[i]) * K + kt + ek[i] * 8, &As[e * 8]);
        }
        #pragma unroll
        for (int i = 0; i < 4; ++i) {
            const int e = i * 256 + tid;
            gld_lds16(W + (size_t)(n0 + em[i]) * K + kt + ek[i] * 8, &Ws[e * 8]);
        }
        __syncthreads();

        #pragma unroll
        for (int ks = 0; ks < 2; ++ks) {
            const int k8 = ks * 4 + quad;
            f16x8 af[4], bf[4];
            #pragma unroll
            for (int i = 0; i < 4; ++i) {
                const int m = wm + i * 16 + l16;
                af[i] = *(const f16x8*)&As[m * 64 + ((k8 ^ (m & 7)) * 8)];
            }
            #pragma unroll
            for (int j = 0; j < 4; ++j) {
                const int n = wn + j * 16 + l16;
                bf[j] = *(const f16x8*)&Ws[n * 64 + ((k8 ^ (n & 7)) * 8)];
            }
            #pragma unroll
            for (int i = 0; i < 4; ++i)
                #pragma unroll
                for (int j = 0; j < 4; ++j)
                    acc[i][j] = __builtin_amdgcn_mfma_f32_16x16x32_f16(af[i], bf[j], acc[i][j], 0, 0, 0);
        }
    }

    const int cbase = n0 + wn + l16;
    const int rbase = m0 + wm + quad * 4;
    #pragma unroll
    for (int j = 0; j < 4; ++j) {
        const int col = cbase + j * 16;
        const float bv = bias[col];
        #pragma unroll
        for (int i = 0; i < 4; ++i) {
            #pragma unroll
            for (int r = 0; r < 4; ++r) {
                const int m = rbase + i * 16 + r;
                C[(size_t)m * N + col] = (CT)(acc[i][j][r] + bv);
            }
        }
    }
}

// ---------------- Flash attention, all-fp16 inputs, bitmask, MFMA ----------
#define QT 64
#define KT 64
#define SP 72
#define EVP 40

__global__ __launch_bounds__(256) void attn_flash_mfma3(
    const _Float16* __restrict__ q, const _Float16* __restrict__ kg,
    const _Float16* __restrict__ v, const u64* __restrict__ mbits,
    const float* __restrict__ emb_k, const float* __restrict__ emb_v,
    _Float16* __restrict__ x)
{
    __shared__ _Float16 Ks[2][KT * SP];
    __shared__ _Float16 Vt[2][HEAD_DIM * SP];
    __shared__ _Float16 Ps[QT * SP];
    __shared__ _Float16 EvT[HEAD_DIM * EVP];
    __shared__ _Float16 pbh[QT * 33];
    __shared__ _Float16 bandh[QT * 33];

    const int qt = blockIdx.x, h = blockIdx.y, b = blockIdx.z;
    const int q0 = qt * QT;
    const int tid = threadIdx.x;
    const int lane = tid & 63;
    const int w = tid >> 6;
    const int quad = lane >> 4;
    const int l16 = lane & 15;
    const int qrow = w * 16 + quad * 4;

    const int sr = tid >> 2, sc = (tid & 3) * 16;
    const int vk = (tid & 31) * 2, vd = (tid >> 5) * 8;
    const int k8 = vk >> 3, klo = vk & 7;

    f16x8 qf[2];
    {
        const _Float16* qp = q + ((size_t)(b*SEQ + q0 + w*16 + l16))*D_MODEL + h*HEAD_DIM;
        qf[0] = *(const f16x8*)(qp + quad*8);
        qf[1] = *(const f16x8*)(qp + 32 + quad*8);
    }

    if (sr < 48) {
        #pragma unroll
        for (int c = 0; c < 16; ++c) {
            float val = (sr < 33) ? emb_k[sr*HEAD_DIM + sc + c] : 0.f;
            Ks[0][sr*SP + sc + c] = (_Float16)val;
        }
    }
    for (int idx = tid; idx < HEAD_DIM*EVP; idx += 256) {
        const int d = idx / EVP, j = idx % EVP;
        float val = (j < 32) ? emb_v[j*HEAD_DIM + d] : 0.f;
        EvT[d*EVP + j] = (_Float16)val;
    }
    for (int i = tid; i < QT*33; i += 256) bandh[i] = (_Float16)(-60000.f);
    __syncthreads();

    f32x4 accP[3];
    #pragma unroll
    for (int jt = 0; jt < 3; ++jt) accP[jt] = (f32x4){0.f,0.f,0.f,0.f};
    #pragma unroll
    for (int ks2 = 0; ks2 < 2; ++ks2) {
        const int ko = ks2*32 + quad*8;
        #pragma unroll
        for (int jt = 0; jt < 3; ++jt) {
            f16x8 bf = *(const f16x8*)&Ks[0][(jt*16 + l16)*SP + ko];
            accP[jt] = __builtin_amdgcn_mfma_f32_16x16x32_f16(qf[ks2], bf, accP[jt], 0, 0, 0);
        }
    }
    #pragma unroll
    for (int jt = 0; jt < 3; ++jt) {
        const int j = jt*16 + l16;
        if (j < 33) {
            #pragma unroll
            for (int r = 0; r < 4; ++r) pbh[(qrow + r)*33 + j] = (_Float16)accP[jt][r];
        }
    }
    float pb0r[4], pb32r[4];
    #pragma unroll
    for (int r = 0; r < 4; ++r) {
        pb0r[r]  = __shfl(accP[0][r], quad * 16);
        pb32r[r] = __shfl(accP[2][r], quad * 16);
    }
    __syncthreads();

    float m_r[4], l_r[4], rt_r[4];
    #pragma unroll
    for (int r = 0; r < 4; ++r) { m_r[r] = -1e30f; l_r[r] = 0.f; rt_r[r] = 0.f; }
    f32x4 accO[4];
    #pragma unroll
    for (int dt = 0; dt < 4; ++dt) accO[dt] = (f32x4){0.f,0.f,0.f,0.f};

    f16x8 kp0, kp1, vp0, vp1;

    {
        const _Float16* kp = kg + ((size_t)(b*SEQ + sr))*D_MODEL + h*HEAD_DIM + sc;
        kp0 = *(const f16x8*)(kp);
        kp1 = *(const f16x8*)(kp + 8);
        const _Float16* vp = v + ((size_t)(b*SEQ + vk))*D_MODEL + h*HEAD_DIM + vd;
        vp0 = *(const f16x8*)(vp);
        vp1 = *(const f16x8*)(vp + D_MODEL);
        *(f16x8*)&Ks[0][sr*SP + sc]     = kp0;
        *(f16x8*)&Ks[0][sr*SP + sc + 8] = kp1;
        #pragma unroll
        for (int i = 0; i < 8; ++i) {
            const int d = vd + i;
            const int xd = (d >> 3) & 7;
            f16x2 pr; pr[0] = vp0[i]; pr[1] = vp1[i];
            *(f16x2*)&Vt[0][d*SP + ((k8 ^ xd) << 3) + klo] = pr;
        }
    }
    __syncthreads();

    const float inv_scale = 0.125f;

    for (int t = 0; t < SEQ/KT; ++t) {
        const int buf = t & 1;
        const int k0 = t * KT;

        if (t + 1 < SEQ/KT) {
            const int kn = k0 + KT;
            const _Float16* kp = kg + ((size_t)(b*SEQ + kn + sr))*D_MODEL + h*HEAD_DIM + sc;
            kp0 = *(const f16x8*)(kp);
            kp1 = *(const f16x8*)(kp + 8);
            const _Float16* vp = v + ((size_t)(b*SEQ + kn + vk))*D_MODEL + h*HEAD_DIM + vd;
            vp0 = *(const f16x8*)(vp);
            vp1 = *(const f16x8*)(vp + D_MODEL);
        }

        u64 mw[4];
        {
            const u64* mb = mbits + ((size_t)(b*SEQ + q0 + qrow)) * (SEQ/64) + t;
            #pragma unroll
            for (int r = 0; r < 4; ++r) mw[r] = mb[(size_t)r * (SEQ/64)];
        }

        f32x4 accS[4];
        #pragma unroll
        for (int jt = 0; jt < 4; ++jt) accS[jt] = (f32x4){0.f,0.f,0.f,0.f};
        #pragma unroll
        for (int ks2 = 0; ks2 < 2; ++ks2) {
            const int ko = ks2*32 + quad*8;
            #pragma unroll
            for (int jt = 0; jt < 4; ++jt) {
                f16x8 bf = *(const f16x8*)&Ks[buf][(jt*16 + l16)*SP + ko];
                accS[jt] = __builtin_amdgcn_mfma_f32_16x16x32_f16(qf[ks2], bf, accS[jt], 0, 0, 0);
            }
        }

        const int kq = k0 - q0;
        const int mode = (kq <= -128) ? 0 : (kq >= 128 ? 2 : 1);

        float rmax[4] = {-1e30f,-1e30f,-1e30f,-1e30f};
        #pragma unroll
        for (int jt = 0; jt < 4; ++jt) {
            const int kl = jt*16 + l16;
            #pragma unroll
            for (int r = 0; r < 4; ++r) {
                float pv;
                if (mode == 0) pv = pb0r[r];
                else if (mode == 2) pv = pb32r[r];
                else {
                    int dk = (k0 + kl) - (q0 + qrow + r);
                    int ii = (dk < -MAX_REL ? -MAX_REL : (dk > MAX_REL ? MAX_REL : dk)) + MAX_REL;
                    pv = (float)pbh[(qrow + r)*33 + ii];
                }
                float s = (accS[jt][r] + pv) * inv_scale;
                if (!((mw[r] >> kl) & 1ull)) s = -1e30f;
                accS[jt][r] = s;
                rmax[r] = fmaxf(rmax[r], s);
            }
        }
        #pragma unroll
        for (int r = 0; r < 4; ++r) {
            #pragma unroll
            for (int d = 1; d < 16; d <<= 1)
                rmax[r] = fmaxf(rmax[r], __shfl_xor(rmax[r], d));
        }
        float alf[4];
        #pragma unroll
        for (int r = 0; r < 4; ++r) {
            const float mn = fmaxf(m_r[r], rmax[r]);
            alf[r] = __expf(m_r[r] - mn);
            m_r[r] = mn;
        }

        float rs[4] = {0,0,0,0}, rts[4] = {0,0,0,0};
        #pragma unroll
        for (int jt = 0; jt < 4; ++jt) {
            const int kl = jt*16 + l16;
            #pragma unroll
            for (int r = 0; r < 4; ++r) {
                const float s = accS[jt][r];
                const float p = __expf(s - m_r[r]);
                rs[r] += p;
                if (mode == 2) rts[r] += p;
                else if (mode == 1) {
                    int dk = (k0 + kl) - (q0 + qrow + r);
                    if (dk > MAX_REL) rts[r] += p;
                    else if (dk >= -MAX_REL) bandh[(qrow + r)*33 + dk + MAX_REL] = (_Float16)s;
                }
                Ps[(qrow + r)*SP + kl] = (_Float16)p;
            }
        }
        #pragma unroll
        for (int r = 0; r < 4; ++r) {
            #pragma unroll
            for (int d = 1; d < 16; d <<= 1) rs[r] += __shfl_xor(rs[r], d);
        }
        if (mode != 0) {
            #pragma unroll
            for (int r = 0; r < 4; ++r) {
                #pragma unroll
                for (int d = 1; d < 16; d <<= 1) rts[r] += __shfl_xor(rts[r], d);
            }
        }
        #pragma unroll
        for (int r = 0; r < 4; ++r) {
            l_r[r]  = l_r[r]  * alf[r] + rs[r];
            rt_r[r] = rt_r[r] * alf[r] + rts[r];
        }
        #pragma unroll
        for (int dt = 0; dt < 4; ++dt)
            #pragma unroll
            for (int r = 0; r < 4; ++r) accO[dt][r] *= alf[r];

        #pragma unroll
        for (int ks2 = 0; ks2 < 2; ++ks2) {
            const int ko = ks2*32 + quad*8;
            const int k8n = ks2*4 + quad;
            f16x8 pf = *(const f16x8*)&Ps[(w*16 + l16)*SP + ko];
            #pragma unroll
            for (int dt = 0; dt < 4; ++dt) {
                const int d = dt*16 + l16;
                const int xd = (d >> 3) & 7;
                f16x8 vf = *(const f16x8*)&Vt[buf][d*SP + ((k8n ^ xd) << 3)];
                accO[dt] = __builtin_amdgcn_mfma_f32_16x16x32_f16(pf, vf, accO[dt], 0, 0, 0);
            }
        }

        if (t + 1 < SEQ/KT) {
            const int nb = buf ^ 1;
            *(f16x8*)&Ks[nb][sr*SP + sc]     = kp0;
            *(f16x8*)&Ks[nb][sr*SP + sc + 8] = kp1;
            #pragma unroll
            for (int i = 0; i < 8; ++i) {
                const int d = vd + i;
                const int xd = (d >> 3) & 7;
                f16x2 pr; pr[0] = vp0[i]; pr[1] = vp1[i];
                *(f16x2*)&Vt[nb][d*SP + ((k8 ^ xd) << 3) + klo] = pr;
            }
        }
        __syncthreads();
    }

    float ej0[4], ej1[4], e32[4], bsp[4];
    #pragma unroll
    for (int r = 0; r < 4; ++r) {
        const int ql = qrow + r;
        ej0[r] = __expf((float)bandh[ql*33 + l16]      - m_r[r]);
        ej1[r] = __expf((float)bandh[ql*33 + 16 + l16] - m_r[r]);
        e32[r] = __expf((float)bandh[ql*33 + 32]       - m_r[r]);
        bsp[r] = ej0[r] + ej1[r];
    }
    #pragma unroll
    for (int r = 0; r < 4; ++r) {
        #pragma unroll
        for (int d = 1; d < 16; d <<= 1) bsp[r] += __shfl_xor(bsp[r], d);
    }
    #pragma unroll
    for (int r = 0; r < 4; ++r) {
        const int ql = qrow + r;
        const float Pl = l_r[r] - rt_r[r] - (bsp[r] + e32[r]);
        Ps[ql*SP + l16]      = (_Float16)((l16 == 0) ? (ej0[r] + Pl) : ej0[r]);
        Ps[ql*SP + 16 + l16] = (_Float16)ej1[r];
    }

    f32x4 accW[4];
    #pragma unroll
    for (int dt = 0; dt < 4; ++dt) accW[dt] = (f32x4){0.f,0.f,0.f,0.f};
    {
        f16x8 pf = *(const f16x8*)&Ps[(w*16 + l16)*SP + quad*8];
        #pragma unroll
        for (int dt = 0; dt < 4; ++dt) {
            f16x8 ef = *(const f16x8*)&EvT[(dt*16 + l16)*EVP + quad*8];
            accW[dt] = __builtin_amdgcn_mfma_f32_16x16x32_f16(pf, ef, accW[dt], 0, 0, 0);
        }
    }
    #pragma unroll
    for (int r = 0; r < 4; ++r) {
        const float p32 = e32[r] + rt_r[r];
        const float linv = 1.f / l_r[r];
        const int qg = q0 + qrow + r;
        #pragma unroll
        for (int dt = 0; dt < 4; ++dt) {
            const float w32 = emb_v[32*HEAD_DIM + dt*16 + l16];
            x[((size_t)(b*SEQ + qg))*D_MODEL + h*HEAD_DIM + dt*16 + l16] =
                (_Float16)((accO[dt][r] + accW[dt][r] + p32 * w32) * linv);
        }
    }
}

extern "C" void kernel_launch(void* const* d_in, const int* in_sizes, int n_in,
                              void* d_out, int out_size, void* d_ws, size_t ws_size,
                              hipStream_t stream) {
    const float* query = (const float*)d_in[0];
    const float* key   = (const float*)d_in[1];
    const float* value = (const float*)d_in[2];
    const int*   mask  = (const int*)d_in[3];
    const float* Wq = (const float*)d_in[4];
    const float* bq = (const float*)d_in[5];
    const float* Wk = (const float*)d_in[6];
    const float* bk = (const float*)d_in[7];
    const float* Wv = (const float*)d_in[8];
    const float* bv = (const float*)d_in[9];
    const float* Wo = (const float*)d_in[10];
    const float* bo = (const float*)d_in[11];
    const float* emb_k = (const float*)d_in[12];
    const float* emb_v = (const float*)d_in[13];
    float* out = (float*)d_out;

    const size_t M1 = 1u << 20;          // 1M elements
    const size_t MD = (size_t)BATCH * SEQ * D_MODEL;  // 4M
    _Float16* ws16 = (_Float16*)d_ws;
    _Float16* qin = ws16;                // [0, 4M)   (xh aliases this later)
    _Float16* kin = ws16 + 4*M1;
    _Float16* vin = ws16 + 8*M1;
    _Float16* qp  = ws16 + 12*M1;
    _Float16* kp  = ws16 + 16*M1;
    _Float16* vp  = ws16 + 20*M1;
    _Float16* wq16 = ws16 + 24*M1;
    _Float16* wk16 = ws16 + 25*M1;
    _Float16* wv16 = ws16 + 26*M1;
    _Float16* wo16 = ws16 + 27*M1;
    u64* mbits = (u64*)(ws16 + 28*M1);
    _Float16* xh = qin;                  // reuse spent input region

    const int Mrows = BATCH * SEQ;       // 4096
    const int n64 = BATCH * SEQ * (SEQ / 64);

    cvt_all<<<dim3(16384), dim3(256), 0, stream>>>(
        query, key, value, Wq, Wk, Wv, Wo,
        qin, kin, vin, wq16, wk16, wv16, wo16);

    mask_compress<<<dim3((n64*64)/256), dim3(256), 0, stream>>>(mask, mbits, n64);

    dim3 gQKV(D_MODEL / TBN, Mrows / TBM, 3), tB(256);
    gemm_f16async<_Float16><<<gQKV, tB, 0, stream>>>(
        qin, kin, vin, wq16, wk16, wv16, bq, bk, bv, qp, kp, vp,
        Mrows, D_MODEL, D_MODEL);

    dim3 gA(SEQ/QT, N_HEADS, BATCH);
    attn_flash_mfma3<<<gA, dim3(256), 0, stream>>>(qp, kp, vp, mbits, emb_k, emb_v, xh);

    dim3 gO(D_MODEL / TBN, Mrows / TBM, 1);
    gemm_f16async<float><<<gO, tB, 0, stream>>>(
        xh, xh, xh, wo16, wo16, wo16, bo, bo, bo, out, out, out,
        Mrows, D_MODEL, D_MODEL);
}